// Round 1
// baseline (1125.680 us; speedup 1.0000x reference)
//
#include <hip/hip_runtime.h>
#include <cstdint>
#include <cstddef>

#pragma clang fp contract(off)

typedef unsigned long long u64;
typedef unsigned int u32;

#define B_IMG 4
#define N_ROI 8192
#define NCLS 80
#define NCOL 81
#define K_NMS 2048
#define CAP 65536
#define MAXOUT 100
#define THR_SCORE 0.05f
#define THR_IOU 0.5f

// ---------------------------------------------------------------------------
// Kernel 1: softmax over 81 cols per RoI (one wave per RoI), threshold > 0.05,
// append (score_bits<<32 | ~flat_idx) keys to per-image candidate list.
// ---------------------------------------------------------------------------
__global__ __launch_bounds__(256) void k_compact(const float* __restrict__ cls,
                                                 u32* __restrict__ counters,
                                                 u64* __restrict__ lists) {
#pragma clang fp contract(off)
  int wid = blockIdx.x * 4 + (threadIdx.x >> 6);  // 0 .. B*N-1
  int lane = threadIdx.x & 63;
  int b = wid >> 13;           // / 8192
  int n = wid & (N_ROI - 1);

  const float* row = cls + (size_t)wid * NCOL;
  float v0 = row[lane];                                     // cols 0..63
  float v1 = (lane < NCOL - 64) ? row[64 + lane] : -1e38f;  // cols 64..80

  float m = fmaxf(v0, v1);
  for (int o = 32; o; o >>= 1) m = fmaxf(m, __shfl_xor(m, o));

  float e0 = expf(v0 - m);
  float e1 = (lane < NCOL - 64) ? expf(v1 - m) : 0.0f;
  float s = e0 + e1;
  for (int o = 32; o; o >>= 1) s += __shfl_xor(s, o);

  float s0 = e0 / s;  // class = lane (0..63)
  float s1 = e1 / s;  // class = 64+lane (lane<16); lane==16 is background

  bool c0 = s0 > THR_SCORE;
  bool c1 = (lane < 16) && (s1 > THR_SCORE);
  u64 b0 = __ballot(c0);
  u64 b1 = __ballot(c1);
  int cnt = __popcll(b0) + __popcll(b1);

  u32 base = 0;
  if (lane == 0 && cnt) base = atomicAdd(&counters[b], (u32)cnt);
  base = __shfl(base, 0);

  u64 lm = (1ull << lane) - 1ull;
  if (c0) {
    int pos = (int)base + __popcll(b0 & lm);
    if (pos < CAP) {
      u32 flat = (u32)(n * NCLS + lane);
      lists[(size_t)b * CAP + pos] = ((u64)__float_as_uint(s0) << 32) | (u32)(~flat);
    }
  }
  if (c1) {
    int pos = (int)base + __popcll(b0) + __popcll(b1 & lm);
    if (pos < CAP) {
      u32 flat = (u32)(n * NCLS + 64 + lane);
      lists[(size_t)b * CAP + pos] = ((u64)__float_as_uint(s1) << 32) | (u32)(~flat);
    }
  }
}

// ---------------------------------------------------------------------------
// Kernel 2: per-image top-2048 by key (desc) via bitonic sort + merge in LDS.
// key order == lax.top_k order: score desc, index asc (~idx in low bits).
// ---------------------------------------------------------------------------
__device__ inline u64 umax64(u64 a, u64 b) { return a > b ? a : b; }

__device__ inline void cmpswap_desc(u64* s, int i, int p, bool desc) {
  u64 a = s[i], b = s[p];
  if ((a < b) == desc) { s[i] = b; s[p] = a; }
}

__device__ void bitonic_sort_desc(u64* s, int t) {
  for (int k = 2; k <= K_NMS; k <<= 1) {
    for (int j = k >> 1; j > 0; j >>= 1) {
      int i = ((t & ~(j - 1)) << 1) | (t & (j - 1));
      cmpswap_desc(s, i, i | j, (i & k) == 0);
      __syncthreads();
    }
  }
}

__device__ void bitonic_clean_desc(u64* s, int t) {
  for (int j = K_NMS >> 1; j > 0; j >>= 1) {
    int i = ((t & ~(j - 1)) << 1) | (t & (j - 1));
    cmpswap_desc(s, i, i | j, true);
    __syncthreads();
  }
}

__global__ __launch_bounds__(1024) void k_select(const u64* __restrict__ lists,
                                                 const u32* __restrict__ counters,
                                                 u64* __restrict__ sorted) {
  __shared__ u64 cur[K_NMS];
  __shared__ u64 chk[K_NMS];
  int b = blockIdx.x;
  int t = threadIdx.x;
  const u64* lst = lists + (size_t)b * CAP;
  int M = (int)counters[b];
  if (M > CAP) M = CAP;

  for (int i = t; i < K_NMS; i += 1024) cur[i] = (i < M) ? lst[i] : 0ull;
  __syncthreads();
  bitonic_sort_desc(cur, t);

  for (int start = K_NMS; start < M; start += K_NMS) {
    for (int i = t; i < K_NMS; i += 1024) {
      int gi = start + i;
      chk[i] = (gi < M) ? lst[gi] : 0ull;
    }
    __syncthreads();
    bitonic_sort_desc(chk, t);
    // top-2048 of union: elementwise max against reversed chunk -> bitonic
    for (int i = t; i < K_NMS; i += 1024) cur[i] = umax64(cur[i], chk[K_NMS - 1 - i]);
    __syncthreads();
    bitonic_clean_desc(cur, t);
  }
  for (int i = t; i < K_NMS; i += 1024) sorted[(size_t)b * K_NMS + i] = cur[i];
}

// ---------------------------------------------------------------------------
// Kernel 3: decode the 2048 selected candidates, replicate reference fp32 math
// exactly (no FMA contraction), produce raw box, offset box (+label*1334 on
// all 4 coords), offset-box area, score, label, flat index.
// ---------------------------------------------------------------------------
__global__ __launch_bounds__(256) void k_decode(const u64* __restrict__ sorted,
                                                const float* __restrict__ props,
                                                const float* __restrict__ regs,
                                                const int* __restrict__ pH,
                                                const int* __restrict__ pW,
                                                float4* __restrict__ raw4,
                                                float4* __restrict__ off4,
                                                float* __restrict__ area,
                                                float* __restrict__ scoref,
                                                int* __restrict__ labeli,
                                                int* __restrict__ flati) {
#pragma clang fp contract(off)
  int t = blockIdx.x * 256 + threadIdx.x;  // 0 .. B*K-1
  int b = t >> 11;
  u64 key = sorted[t];
  if (key == 0ull) {
    raw4[t] = make_float4(0.f, 0.f, 0.f, 0.f);
    off4[t] = make_float4(0.f, 0.f, 0.f, 0.f);
    area[t] = 0.f; scoref[t] = -1.0f; labeli[t] = 0; flati[t] = 0;
    return;
  }
  float Hf = (float)pH[0];
  float Wf = (float)pW[0];
  float offc = fmaxf(Hf, Wf) + 1.0f;  // 1334

  u32 flat = ~(u32)(key & 0xFFFFFFFFull);
  float sc = __uint_as_float((u32)(key >> 32));
  int n = (int)(flat / NCLS);
  int c = (int)(flat - (u32)n * NCLS);

  float4 p = ((const float4*)props)[b * N_ROI + n];
  const float4 dl = *(const float4*)(regs + ((size_t)(b * N_ROI + n)) * (NCLS * 4) + c * 4);

  float mr = fabsf(logf(16.0f / 1000.0f));
  float dx = dl.x * 0.1f;
  float dy = dl.y * 0.1f;
  float dw = fminf(fmaxf(dl.z * 0.2f, -mr), mr);
  float dh = fminf(fmaxf(dl.w * 0.2f, -mr), mr);

  float px = (p.x + p.z) * 0.5f;
  float py = (p.y + p.w) * 0.5f;
  float pw = p.z - p.x;
  float ph = p.w - p.y;

  float tx = pw * dx; float gx = px + tx;
  float ty = ph * dy; float gy = py + ty;
  float gw = pw * expf(dw);
  float gh = ph * expf(dh);
  float hx = gw * 0.5f, hy = gh * 0.5f;

  float x1 = fminf(fmaxf(gx - hx, 0.0f), Wf);
  float y1 = fminf(fmaxf(gy - hy, 0.0f), Hf);
  float x2 = fminf(fmaxf(gx + hx, 0.0f), Wf);
  float y2 = fminf(fmaxf(gy + hy, 0.0f), Hf);

  raw4[t] = make_float4(x1, y1, x2, y2);

  float off = (float)c * offc;
  float ox1 = x1 + off, oy1 = y1 + off, ox2 = x2 + off, oy2 = y2 + off;
  off4[t] = make_float4(ox1, oy1, ox2, oy2);
  area[t] = fmaxf(ox2 - ox1, 0.0f) * fmaxf(oy2 - oy1, 0.0f);
  scoref[t] = sc;
  labeli[t] = c;
  flati[t] = (int)flat;
}

// ---------------------------------------------------------------------------
// Kernel 4: suppression bitmask. Row i: bit j set iff (j>i) && IoU(i,j)>0.5,
// IoU computed on offset boxes exactly as the reference.
// One wave per row; 32 u64 words per row.
// ---------------------------------------------------------------------------
__global__ __launch_bounds__(256) void k_mask(const float4* __restrict__ off4,
                                              const float* __restrict__ area,
                                              u64* __restrict__ masks) {
#pragma clang fp contract(off)
  int wave = threadIdx.x >> 6, lane = threadIdx.x & 63;
  int R = blockIdx.x * 4 + wave;  // 0 .. B*K-1
  int b = R >> 11, i = R & (K_NMS - 1);
  const float4* bb = off4 + (size_t)b * K_NMS;
  const float* aa = area + (size_t)b * K_NMS;
  float4 bi = bb[i];
  float ai = aa[i];
  u64 my = 0;
  for (int w = 0; w < 32; ++w) {
    int j = (w << 6) + lane;
    float4 bj = bb[j];
    float lx = fmaxf(bi.x, bj.x);
    float ly = fmaxf(bi.y, bj.y);
    float rx = fminf(bi.z, bj.z);
    float ry = fminf(bi.w, bj.w);
    float ww = fmaxf(rx - lx, 0.0f);
    float hh = fmaxf(ry - ly, 0.0f);
    float inter = ww * hh;
    float uni = (ai + aa[j]) - inter;
    float iou = inter / fmaxf(uni, 1e-6f);
    bool sup = (j > i) && (iou > THR_IOU);
    u64 word = __ballot(sup);
    if (lane == w) my = word;
  }
  if (lane < 32) masks[((size_t)R << 5) + lane] = my;
}

// ---------------------------------------------------------------------------
// Kernel 5: serial greedy scan (one wave per image; lanes 0..31 own 64-bit
// keep words) + top-100 output. 8-deep register prefetch of mask rows.
// ---------------------------------------------------------------------------
__global__ __launch_bounds__(64) void k_scanout(const u64* __restrict__ masks,
                                                const float* __restrict__ scoref,
                                                const float4* __restrict__ raw4,
                                                const int* __restrict__ labeli,
                                                const int* __restrict__ flati,
                                                float* __restrict__ out) {
  int b = blockIdx.x;
  int lane = threadIdx.x;

  // keep init: valid = score > 0
  u64 kw = 0;
  for (int w = 0; w < 32; ++w) {
    bool pred = scoref[(size_t)b * K_NMS + (w << 6) + lane] > 0.0f;
    u64 word = __ballot(pred);
    if (lane == w) kw = word;
  }

  const u64* mrow = masks + ((size_t)b << 16);  // b * 2048 * 32
  u64 q[8];
#pragma unroll
  for (int d = 0; d < 8; ++d) q[d] = (lane < 32) ? mrow[(d << 5) + lane] : 0ull;

  for (int ii = 0; ii < K_NMS; ii += 8) {
#pragma unroll
    for (int d = 0; d < 8; ++d) {
      int i = ii + d;
      u64 cm = q[d];
      int nx = i + 8;
      if (nx < K_NMS) q[d] = (lane < 32) ? mrow[((size_t)nx << 5) + lane] : 0ull;
      u64 kwi = __shfl(kw, i >> 6);
      if ((kwi >> (i & 63)) & 1ull) kw &= ~cm;
    }
  }

  // rank kept candidates (already score-desc order) and emit top-100
  int pc = (lane < 32) ? __popcll(kw) : 0;
  int pre = pc;
  for (int o = 1; o < 64; o <<= 1) {
    int v = __shfl_up(pre, o);
    if (lane >= o) pre += v;
  }
  int excl = pre - pc;
  int total = __shfl(pre, 63);

  float* ob = out;                              // [B,100,4]
  float* os = out + B_IMG * MAXOUT * 4;         // [B,100]
  float* ol = os + B_IMG * MAXOUT;              // [B,100]
  float* oi = ol + B_IMG * MAXOUT;              // [B,100]

  if (lane < 32) {
    u64 w = kw;
    int r = excl;
    while (w) {
      int bit = __ffsll((long long)w) - 1;
      w &= w - 1;
      if (r < MAXOUT) {
        int j = (lane << 6) + bit;
        size_t g = (size_t)b * K_NMS + j;
        float4 bx = raw4[g];
        int o = b * MAXOUT + r;
        ob[o * 4 + 0] = bx.x; ob[o * 4 + 1] = bx.y;
        ob[o * 4 + 2] = bx.z; ob[o * 4 + 3] = bx.w;
        os[o] = scoref[g];
        ol[o] = (float)labeli[g];
        oi[o] = (float)flati[g];
      }
      ++r;
    }
  }
  for (int r = total + lane; r < MAXOUT; r += 64) {
    int o = b * MAXOUT + r;
    ob[o * 4 + 0] = 0.f; ob[o * 4 + 1] = 0.f; ob[o * 4 + 2] = 0.f; ob[o * 4 + 3] = 0.f;
    os[o] = 0.f;
    ol[o] = -1.0f;
    oi[o] = -1.0f;
  }
}

// ---------------------------------------------------------------------------
extern "C" void kernel_launch(void* const* d_in, const int* in_sizes, int n_in,
                              void* d_out, int out_size, void* d_ws, size_t ws_size,
                              hipStream_t stream) {
  const float* cls = (const float*)d_in[0];
  const float* regs = (const float*)d_in[1];
  const float* props = (const float*)d_in[2];
  const int* pH = (const int*)d_in[3];
  const int* pW = (const int*)d_in[4];

  char* ws = (char*)d_ws;
  size_t o = 0;
  u32* counters = (u32*)(ws + o); o += 256;
  u64* lists = (u64*)(ws + o); o += (size_t)B_IMG * CAP * sizeof(u64);
  u64* sorted = (u64*)(ws + o); o += (size_t)B_IMG * K_NMS * sizeof(u64);
  float4* raw4 = (float4*)(ws + o); o += (size_t)B_IMG * K_NMS * sizeof(float4);
  float4* off4 = (float4*)(ws + o); o += (size_t)B_IMG * K_NMS * sizeof(float4);
  float* area = (float*)(ws + o); o += (size_t)B_IMG * K_NMS * sizeof(float);
  float* scoref = (float*)(ws + o); o += (size_t)B_IMG * K_NMS * sizeof(float);
  int* labeli = (int*)(ws + o); o += (size_t)B_IMG * K_NMS * sizeof(int);
  int* flati = (int*)(ws + o); o += (size_t)B_IMG * K_NMS * sizeof(int);
  u64* masks = (u64*)(ws + o); o += (size_t)B_IMG * K_NMS * 32 * sizeof(u64);

  hipMemsetAsync(counters, 0, 256, stream);
  k_compact<<<B_IMG * N_ROI / 4, 256, 0, stream>>>(cls, counters, lists);
  k_select<<<B_IMG, 1024, 0, stream>>>(lists, counters, sorted);
  k_decode<<<B_IMG * K_NMS / 256, 256, 0, stream>>>(sorted, props, regs, pH, pW,
                                                    raw4, off4, area, scoref, labeli, flati);
  k_mask<<<B_IMG * K_NMS / 4, 256, 0, stream>>>(off4, area, masks);
  k_scanout<<<B_IMG, 64, 0, stream>>>(masks, scoref, raw4, labeli, flati, (float*)d_out);
}

// Round 2
// 704.197 us; speedup vs baseline: 1.5985x; 1.5985x over previous
//
#include <hip/hip_runtime.h>
#include <cstdint>
#include <cstddef>

#pragma clang fp contract(off)

typedef unsigned long long u64;
typedef unsigned int u32;

#define B_IMG 4
#define N_ROI 8192
#define NCLS 80
#define NCOL 81
#define K_NMS 2048
#define CAP 65536
#define MAXOUT 100
#define THR_SCORE 0.05f
#define THR_IOU 0.5f

// ---------------------------------------------------------------------------
// Kernel 1: softmax over 81 cols per RoI (one wave per RoI), threshold > 0.05,
// append (score_bits<<32 | ~flat_idx) keys to per-image candidate list.
// ---------------------------------------------------------------------------
__global__ __launch_bounds__(256) void k_compact(const float* __restrict__ cls,
                                                 u32* __restrict__ counters,
                                                 u64* __restrict__ lists) {
#pragma clang fp contract(off)
  int wid = blockIdx.x * 4 + (threadIdx.x >> 6);  // 0 .. B*N-1
  int lane = threadIdx.x & 63;
  int b = wid >> 13;           // / 8192
  int n = wid & (N_ROI - 1);

  const float* row = cls + (size_t)wid * NCOL;
  float v0 = row[lane];                                     // cols 0..63
  float v1 = (lane < NCOL - 64) ? row[64 + lane] : -1e38f;  // cols 64..80

  float m = fmaxf(v0, v1);
  for (int o = 32; o; o >>= 1) m = fmaxf(m, __shfl_xor(m, o));

  float e0 = expf(v0 - m);
  float e1 = (lane < NCOL - 64) ? expf(v1 - m) : 0.0f;
  float s = e0 + e1;
  for (int o = 32; o; o >>= 1) s += __shfl_xor(s, o);

  float s0 = e0 / s;  // class = lane (0..63)
  float s1 = e1 / s;  // class = 64+lane (lane<16); lane==16 is background

  bool c0 = s0 > THR_SCORE;
  bool c1 = (lane < 16) && (s1 > THR_SCORE);
  u64 b0 = __ballot(c0);
  u64 b1 = __ballot(c1);
  int cnt = __popcll(b0) + __popcll(b1);

  u32 base = 0;
  if (lane == 0 && cnt) base = atomicAdd(&counters[b], (u32)cnt);
  base = __shfl(base, 0);

  u64 lm = (1ull << lane) - 1ull;
  if (c0) {
    int pos = (int)base + __popcll(b0 & lm);
    if (pos < CAP) {
      u32 flat = (u32)(n * NCLS + lane);
      lists[(size_t)b * CAP + pos] = ((u64)__float_as_uint(s0) << 32) | (u32)(~flat);
    }
  }
  if (c1) {
    int pos = (int)base + __popcll(b0) + __popcll(b1 & lm);
    if (pos < CAP) {
      u32 flat = (u32)(n * NCLS + 64 + lane);
      lists[(size_t)b * CAP + pos] = ((u64)__float_as_uint(s1) << 32) | (u32)(~flat);
    }
  }
}

// ---------------------------------------------------------------------------
// Kernel 2: per-image top-2048 by key (desc) via bitonic sort + merge in LDS.
// key order == lax.top_k order: score desc, index asc (~idx in low bits).
// ---------------------------------------------------------------------------
__device__ inline u64 umax64(u64 a, u64 b) { return a > b ? a : b; }

__device__ inline void cmpswap_desc(u64* s, int i, int p, bool desc) {
  u64 a = s[i], b = s[p];
  if ((a < b) == desc) { s[i] = b; s[p] = a; }
}

__device__ void bitonic_sort_desc(u64* s, int t) {
  for (int k = 2; k <= K_NMS; k <<= 1) {
    for (int j = k >> 1; j > 0; j >>= 1) {
      int i = ((t & ~(j - 1)) << 1) | (t & (j - 1));
      cmpswap_desc(s, i, i | j, (i & k) == 0);
      __syncthreads();
    }
  }
}

__device__ void bitonic_clean_desc(u64* s, int t) {
  for (int j = K_NMS >> 1; j > 0; j >>= 1) {
    int i = ((t & ~(j - 1)) << 1) | (t & (j - 1));
    cmpswap_desc(s, i, i | j, true);
    __syncthreads();
  }
}

__global__ __launch_bounds__(1024) void k_select(const u64* __restrict__ lists,
                                                 const u32* __restrict__ counters,
                                                 u64* __restrict__ sorted) {
  __shared__ u64 cur[K_NMS];
  __shared__ u64 chk[K_NMS];
  int b = blockIdx.x;
  int t = threadIdx.x;
  const u64* lst = lists + (size_t)b * CAP;
  int M = (int)counters[b];
  if (M > CAP) M = CAP;

  for (int i = t; i < K_NMS; i += 1024) cur[i] = (i < M) ? lst[i] : 0ull;
  __syncthreads();
  bitonic_sort_desc(cur, t);

  for (int start = K_NMS; start < M; start += K_NMS) {
    for (int i = t; i < K_NMS; i += 1024) {
      int gi = start + i;
      chk[i] = (gi < M) ? lst[gi] : 0ull;
    }
    __syncthreads();
    bitonic_sort_desc(chk, t);
    // top-2048 of union: elementwise max against reversed chunk -> bitonic
    for (int i = t; i < K_NMS; i += 1024) cur[i] = umax64(cur[i], chk[K_NMS - 1 - i]);
    __syncthreads();
    bitonic_clean_desc(cur, t);
  }
  for (int i = t; i < K_NMS; i += 1024) sorted[(size_t)b * K_NMS + i] = cur[i];
}

// ---------------------------------------------------------------------------
// Kernel 3: decode the 2048 selected candidates, replicate reference fp32 math
// exactly (no FMA contraction), produce raw box, offset box (+label*1334 on
// all 4 coords), offset-box area, score, label, flat index.
// ---------------------------------------------------------------------------
__global__ __launch_bounds__(256) void k_decode(const u64* __restrict__ sorted,
                                                const float* __restrict__ props,
                                                const float* __restrict__ regs,
                                                const int* __restrict__ pH,
                                                const int* __restrict__ pW,
                                                float4* __restrict__ raw4,
                                                float4* __restrict__ off4,
                                                float* __restrict__ area,
                                                float* __restrict__ scoref,
                                                int* __restrict__ labeli,
                                                int* __restrict__ flati) {
#pragma clang fp contract(off)
  int t = blockIdx.x * 256 + threadIdx.x;  // 0 .. B*K-1
  int b = t >> 11;
  u64 key = sorted[t];
  if (key == 0ull) {
    raw4[t] = make_float4(0.f, 0.f, 0.f, 0.f);
    off4[t] = make_float4(0.f, 0.f, 0.f, 0.f);
    area[t] = 0.f; scoref[t] = -1.0f; labeli[t] = 0; flati[t] = 0;
    return;
  }
  float Hf = (float)pH[0];
  float Wf = (float)pW[0];
  float offc = fmaxf(Hf, Wf) + 1.0f;  // 1334

  u32 flat = ~(u32)(key & 0xFFFFFFFFull);
  float sc = __uint_as_float((u32)(key >> 32));
  int n = (int)(flat / NCLS);
  int c = (int)(flat - (u32)n * NCLS);

  float4 p = ((const float4*)props)[b * N_ROI + n];
  const float4 dl = *(const float4*)(regs + ((size_t)(b * N_ROI + n)) * (NCLS * 4) + c * 4);

  float mr = fabsf(logf(16.0f / 1000.0f));
  float dx = dl.x * 0.1f;
  float dy = dl.y * 0.1f;
  float dw = fminf(fmaxf(dl.z * 0.2f, -mr), mr);
  float dh = fminf(fmaxf(dl.w * 0.2f, -mr), mr);

  float px = (p.x + p.z) * 0.5f;
  float py = (p.y + p.w) * 0.5f;
  float pw = p.z - p.x;
  float ph = p.w - p.y;

  float tx = pw * dx; float gx = px + tx;
  float ty = ph * dy; float gy = py + ty;
  float gw = pw * expf(dw);
  float gh = ph * expf(dh);
  float hx = gw * 0.5f, hy = gh * 0.5f;

  float x1 = fminf(fmaxf(gx - hx, 0.0f), Wf);
  float y1 = fminf(fmaxf(gy - hy, 0.0f), Hf);
  float x2 = fminf(fmaxf(gx + hx, 0.0f), Wf);
  float y2 = fminf(fmaxf(gy + hy, 0.0f), Hf);

  raw4[t] = make_float4(x1, y1, x2, y2);

  float off = (float)c * offc;
  float ox1 = x1 + off, oy1 = y1 + off, ox2 = x2 + off, oy2 = y2 + off;
  off4[t] = make_float4(ox1, oy1, ox2, oy2);
  area[t] = fmaxf(ox2 - ox1, 0.0f) * fmaxf(oy2 - oy1, 0.0f);
  scoref[t] = sc;
  labeli[t] = c;
  flati[t] = (int)flat;
}

// ---------------------------------------------------------------------------
// Kernel 4: suppression bitmask. Row i: bit j set iff (j>i) && IoU(i,j)>0.5,
// IoU computed on offset boxes exactly as the reference.
// One wave per row; 32 u64 words per row.
// ---------------------------------------------------------------------------
__global__ __launch_bounds__(256) void k_mask(const float4* __restrict__ off4,
                                              const float* __restrict__ area,
                                              u64* __restrict__ masks) {
#pragma clang fp contract(off)
  int wave = threadIdx.x >> 6, lane = threadIdx.x & 63;
  int R = blockIdx.x * 4 + wave;  // 0 .. B*K-1
  int b = R >> 11, i = R & (K_NMS - 1);
  const float4* bb = off4 + (size_t)b * K_NMS;
  const float* aa = area + (size_t)b * K_NMS;
  float4 bi = bb[i];
  float ai = aa[i];
  u64 my = 0;
  for (int w = 0; w < 32; ++w) {
    int j = (w << 6) + lane;
    float4 bj = bb[j];
    float lx = fmaxf(bi.x, bj.x);
    float ly = fmaxf(bi.y, bj.y);
    float rx = fminf(bi.z, bj.z);
    float ry = fminf(bi.w, bj.w);
    float ww = fmaxf(rx - lx, 0.0f);
    float hh = fmaxf(ry - ly, 0.0f);
    float inter = ww * hh;
    float uni = (ai + aa[j]) - inter;
    float iou = inter / fmaxf(uni, 1e-6f);
    bool sup = (j > i) && (iou > THR_IOU);
    u64 word = __ballot(sup);
    if (lane == w) my = word;
  }
  if (lane < 32) masks[((size_t)R << 5) + lane] = my;
}

// ---------------------------------------------------------------------------
// Kernel 5: serial greedy scan (one wave per image; lanes 0..31 own 64-bit
// keep words) + top-100 output. 16-deep prefetch in NAMED registers (rule
// #20: no runtime-indexed arrays -> no scratch). Mask buffer has a 16-row
// pad at the end so the tail prefetch needs no branch.
// ---------------------------------------------------------------------------
__global__ __launch_bounds__(64) void k_scanout(const u64* __restrict__ masks,
                                                const float* __restrict__ scoref,
                                                const float4* __restrict__ raw4,
                                                const int* __restrict__ labeli,
                                                const int* __restrict__ flati,
                                                float* __restrict__ out) {
  int b = blockIdx.x;
  int lane = threadIdx.x;

  // keep init: valid = score > 0
  u64 kw = 0;
  for (int w = 0; w < 32; ++w) {
    bool pred = scoref[(size_t)b * K_NMS + (w << 6) + lane] > 0.0f;
    u64 word = __ballot(pred);
    if (lane == w) kw = word;
  }

  const u64* mrow = masks + ((size_t)b << 16);  // b * 2048 * 32
  bool act = lane < 32;

#define LDROW(r) (act ? mrow[((size_t)(r) << 5) + lane] : 0ull)

  u64 q0 = LDROW(0), q1 = LDROW(1), q2 = LDROW(2), q3 = LDROW(3);
  u64 q4 = LDROW(4), q5 = LDROW(5), q6 = LDROW(6), q7 = LDROW(7);
  u64 q8 = LDROW(8), q9 = LDROW(9), q10 = LDROW(10), q11 = LDROW(11);
  u64 q12 = LDROW(12), q13 = LDROW(13), q14 = LDROW(14), q15 = LDROW(15);

#define STEP(d, qv)                                   \
  {                                                   \
    int i = ii + (d);                                 \
    u64 cm = qv;                                      \
    qv = LDROW(i + 16); /* pad rows make this safe */ \
    u64 kwi = __shfl(kw, i >> 6);                     \
    if ((kwi >> (i & 63)) & 1ull) kw &= ~cm;          \
  }

  for (int ii = 0; ii < K_NMS; ii += 16) {
    STEP(0, q0)  STEP(1, q1)  STEP(2, q2)  STEP(3, q3)
    STEP(4, q4)  STEP(5, q5)  STEP(6, q6)  STEP(7, q7)
    STEP(8, q8)  STEP(9, q9)  STEP(10, q10) STEP(11, q11)
    STEP(12, q12) STEP(13, q13) STEP(14, q14) STEP(15, q15)
  }
#undef STEP
#undef LDROW

  // rank kept candidates (already score-desc order) and emit top-100
  int pc = (lane < 32) ? __popcll(kw) : 0;
  int pre = pc;
  for (int o = 1; o < 64; o <<= 1) {
    int v = __shfl_up(pre, o);
    if (lane >= o) pre += v;
  }
  int excl = pre - pc;
  int total = __shfl(pre, 63);

  float* ob = out;                              // [B,100,4]
  float* os = out + B_IMG * MAXOUT * 4;         // [B,100]
  float* ol = os + B_IMG * MAXOUT;              // [B,100]
  float* oi = ol + B_IMG * MAXOUT;              // [B,100]

  if (lane < 32) {
    u64 w = kw;
    int r = excl;
    while (w) {
      int bit = __ffsll((long long)w) - 1;
      w &= w - 1;
      if (r < MAXOUT) {
        int j = (lane << 6) + bit;
        size_t g = (size_t)b * K_NMS + j;
        float4 bx = raw4[g];
        int o = b * MAXOUT + r;
        ob[o * 4 + 0] = bx.x; ob[o * 4 + 1] = bx.y;
        ob[o * 4 + 2] = bx.z; ob[o * 4 + 3] = bx.w;
        os[o] = scoref[g];
        ol[o] = (float)labeli[g];
        oi[o] = (float)flati[g];
      }
      ++r;
    }
  }
  for (int r = total + lane; r < MAXOUT; r += 64) {
    int o = b * MAXOUT + r;
    ob[o * 4 + 0] = 0.f; ob[o * 4 + 1] = 0.f; ob[o * 4 + 2] = 0.f; ob[o * 4 + 3] = 0.f;
    os[o] = 0.f;
    ol[o] = -1.0f;
    oi[o] = -1.0f;
  }
}

// ---------------------------------------------------------------------------
extern "C" void kernel_launch(void* const* d_in, const int* in_sizes, int n_in,
                              void* d_out, int out_size, void* d_ws, size_t ws_size,
                              hipStream_t stream) {
  const float* cls = (const float*)d_in[0];
  const float* regs = (const float*)d_in[1];
  const float* props = (const float*)d_in[2];
  const int* pH = (const int*)d_in[3];
  const int* pW = (const int*)d_in[4];

  char* ws = (char*)d_ws;
  size_t o = 0;
  u32* counters = (u32*)(ws + o); o += 256;
  u64* lists = (u64*)(ws + o); o += (size_t)B_IMG * CAP * sizeof(u64);
  u64* sorted = (u64*)(ws + o); o += (size_t)B_IMG * K_NMS * sizeof(u64);
  float4* raw4 = (float4*)(ws + o); o += (size_t)B_IMG * K_NMS * sizeof(float4);
  float4* off4 = (float4*)(ws + o); o += (size_t)B_IMG * K_NMS * sizeof(float4);
  float* area = (float*)(ws + o); o += (size_t)B_IMG * K_NMS * sizeof(float);
  float* scoref = (float*)(ws + o); o += (size_t)B_IMG * K_NMS * sizeof(float);
  int* labeli = (int*)(ws + o); o += (size_t)B_IMG * K_NMS * sizeof(int);
  int* flati = (int*)(ws + o); o += (size_t)B_IMG * K_NMS * sizeof(int);
  u64* masks = (u64*)(ws + o); o += (size_t)B_IMG * K_NMS * 32 * sizeof(u64);
  o += 16 * 32 * sizeof(u64);  // 4 KB pad: tail prefetch reads 16 rows past the end

  hipMemsetAsync(counters, 0, 256, stream);
  k_compact<<<B_IMG * N_ROI / 4, 256, 0, stream>>>(cls, counters, lists);
  k_select<<<B_IMG, 1024, 0, stream>>>(lists, counters, sorted);
  k_decode<<<B_IMG * K_NMS / 256, 256, 0, stream>>>(sorted, props, regs, pH, pW,
                                                    raw4, off4, area, scoref, labeli, flati);
  k_mask<<<B_IMG * K_NMS / 4, 256, 0, stream>>>(off4, area, masks);
  k_scanout<<<B_IMG, 64, 0, stream>>>(masks, scoref, raw4, labeli, flati, (float*)d_out);
}

// Round 3
// 277.829 us; speedup vs baseline: 4.0517x; 2.5346x over previous
//
#include <hip/hip_runtime.h>
#include <cstdint>
#include <cstddef>

#pragma clang fp contract(off)

typedef unsigned long long u64;
typedef unsigned int u32;

#define B_IMG 4
#define N_ROI 8192
#define NCLS 80
#define NCOL 81
#define K_NMS 2048
#define MAXOUT 100
#define THR_SCORE 0.05f
#define THR_IOU 0.5f

#define NBIN 4096
#define BIN_OFF 62771u  // (0x3D4CCCCD >> 14): bin of smallest float > 0.05f
#define NSEG 16
#define GSEGCAP 512
#define SORTN 4096

// ---------------------------------------------------------------------------
// Shared softmax: MUST be bit-identical between k_hist and k_gather (it is:
// same inline function, same reduction order, IEEE ops, contract off).
// s0 = score of class `lane` (0..63); s1 = score of class 64+lane (lane<16).
// ---------------------------------------------------------------------------
__device__ __forceinline__ void softmax_row(const float* __restrict__ row, int lane,
                                            float& s0, float& s1) {
  float v0 = row[lane];
  float v1 = (lane < NCOL - 64) ? row[64 + lane] : -1e38f;
  float m = fmaxf(v0, v1);
  for (int o = 32; o; o >>= 1) m = fmaxf(m, __shfl_xor(m, o));
  float e0 = expf(v0 - m);
  float e1 = (lane < NCOL - 64) ? expf(v1 - m) : 0.0f;
  float s = e0 + e1;
  for (int o = 32; o; o >>= 1) s += __shfl_xor(s, o);
  s0 = e0 / s;
  s1 = e1 / s;
}

// ---------------------------------------------------------------------------
// Kernel 1: per-image 4096-bin histogram of candidate score keys.
// 1024 threads = 16 waves = 16 RoIs per block; LDS-aggregated.
// ---------------------------------------------------------------------------
__global__ __launch_bounds__(1024) void k_hist(const float* __restrict__ cls,
                                               u32* __restrict__ hist) {
#pragma clang fp contract(off)
  __shared__ u32 lh[NBIN];
  int t = threadIdx.x;
  for (int i = t; i < NBIN; i += 1024) lh[i] = 0;
  __syncthreads();
  int wv = t >> 6, lane = t & 63;
  int wid = blockIdx.x * 16 + wv;  // 16 divides 8192 -> block within one image
  int b = wid >> 13;
  float s0, s1;
  softmax_row(cls + (size_t)wid * NCOL, lane, s0, s1);
  if (s0 > THR_SCORE) atomicAdd(&lh[(__float_as_uint(s0) >> 14) - BIN_OFF], 1u);
  if (lane < 16 && s1 > THR_SCORE) atomicAdd(&lh[(__float_as_uint(s1) >> 14) - BIN_OFF], 1u);
  __syncthreads();
  u32* gh = hist + (size_t)b * NBIN;
  for (int i = t; i < NBIN; i += 1024) {
    u32 c = lh[i];
    if (c) atomicAdd(&gh[i], c);
  }
}

// ---------------------------------------------------------------------------
// Kernel 2: per image, find largest bin c* with suffix_count(c*) >= 2048.
// (If total < 2048, c* = 0.) prefix(c) = #items in bins < c.
// ---------------------------------------------------------------------------
__global__ __launch_bounds__(1024) void k_cutoff(const u32* __restrict__ hist,
                                                 u32* __restrict__ cut) {
  __shared__ u32 wsum[16];
  __shared__ int best;
  int b = blockIdx.x, t = threadIdx.x;
  const u32* gh = hist + (size_t)b * NBIN;
  u32 v0 = gh[t * 4 + 0], v1 = gh[t * 4 + 1], v2 = gh[t * 4 + 2], v3 = gh[t * 4 + 3];
  u32 my = v0 + v1 + v2 + v3;
  int lane = t & 63, wv = t >> 6;
  u32 inc = my;
  for (int o = 1; o < 64; o <<= 1) {
    u32 x = __shfl_up(inc, o);
    if (lane >= o) inc += x;
  }
  if (lane == 63) wsum[wv] = inc;
  if (t == 0) best = 0;
  __syncthreads();
  u32 wpre = 0;
  for (int i = 0; i < wv; ++i) wpre += wsum[i];
  u32 total = 0;
  for (int i = 0; i < 16; ++i) total += wsum[i];
  u32 excl = wpre + (inc - my);  // prefix(bin t*4)
  if (total >= K_NMS) {
    u32 lim = total - K_NMS;
    u32 p = excl;
    int cand = -1;
    if (p <= lim) cand = t * 4 + 0; p += v0;
    if (p <= lim) cand = t * 4 + 1; p += v1;
    if (p <= lim) cand = t * 4 + 2; p += v2;
    if (p <= lim) cand = t * 4 + 3; p += v3;
    if (cand >= 0) atomicMax(&best, cand);
  }
  __syncthreads();
  if (t == 0) cut[b] = (total >= K_NMS) ? (u32)best : 0u;
}

// ---------------------------------------------------------------------------
// Kernel 3: recompute softmax, append items with bin >= cut[b] to 16 segments
// per image. Block-aggregated atomics: <=32 serialized atomics per counter.
// ---------------------------------------------------------------------------
__global__ __launch_bounds__(1024) void k_gather(const float* __restrict__ cls,
                                                 const u32* __restrict__ cut,
                                                 u32* __restrict__ gcnt,
                                                 u64* __restrict__ glist) {
#pragma clang fp contract(off)
  __shared__ u32 wbase[16];
  __shared__ u32 blkcnt;
  __shared__ u32 gbase;
  int t = threadIdx.x, wv = t >> 6, lane = t & 63;
  int wid = blockIdx.x * 16 + wv;
  int b = wid >> 13;
  int n = wid & (N_ROI - 1);
  if (t == 0) blkcnt = 0;
  __syncthreads();
  float s0, s1;
  softmax_row(cls + (size_t)wid * NCOL, lane, s0, s1);
  u32 c = cut[b];
  bool c0 = (s0 > THR_SCORE) && (((__float_as_uint(s0) >> 14) - BIN_OFF) >= c);
  bool c1 = (lane < 16) && (s1 > THR_SCORE) && (((__float_as_uint(s1) >> 14) - BIN_OFF) >= c);
  u64 b0 = __ballot(c0), b1 = __ballot(c1);
  int cnt = __popcll(b0) + __popcll(b1);
  if (lane == 0) wbase[wv] = atomicAdd(&blkcnt, (u32)cnt);
  __syncthreads();
  int seg = blockIdx.x & (NSEG - 1);  // 512 blocks/image -> 32 blocks/segment
  if (t == 0) gbase = atomicAdd(&gcnt[b * NSEG + seg], blkcnt);
  __syncthreads();
  u32 base = gbase + wbase[wv];
  u64 lm = (1ull << lane) - 1ull;
  u64* seglist = glist + ((size_t)(b * NSEG + seg)) * GSEGCAP;
  if (c0) {
    u32 pos = base + (u32)__popcll(b0 & lm);
    if (pos < GSEGCAP) {
      u32 flat = (u32)(n * NCLS + lane);
      seglist[pos] = ((u64)__float_as_uint(s0) << 32) | (u32)(~flat);
    }
  }
  if (c1) {
    u32 pos = base + (u32)__popcll(b0) + (u32)__popcll(b1 & lm);
    if (pos < GSEGCAP) {
      u32 flat = (u32)(n * NCLS + 64 + lane);
      seglist[pos] = ((u64)__float_as_uint(s1) << 32) | (u32)(~flat);
    }
  }
}

// ---------------------------------------------------------------------------
// Kernel 4: per-image bitonic sort (desc) of <=4096 gathered keys in LDS;
// emit sorted top-2048. Full-key sort -> deterministic despite append order.
// ---------------------------------------------------------------------------
__device__ inline void cmpswap_desc(u64* s, int i, int p, bool desc) {
  u64 a = s[i], b = s[p];
  if ((a < b) == desc) { s[i] = b; s[p] = a; }
}

__global__ __launch_bounds__(1024) void k_sort(const u32* __restrict__ gcnt,
                                               const u64* __restrict__ glist,
                                               u64* __restrict__ sorted) {
  __shared__ u64 s[SORTN];
  __shared__ u32 pref[NSEG + 1];
  int b = blockIdx.x, t = threadIdx.x;
  if (t == 0) {
    u32 p = 0;
    for (int i = 0; i < NSEG; ++i) {
      pref[i] = p;
      u32 cc = gcnt[b * NSEG + i];
      if (cc > GSEGCAP) cc = GSEGCAP;
      p += cc;
    }
    pref[NSEG] = p;
  }
  __syncthreads();
  u32 T = pref[NSEG];
  if (T > SORTN) T = SORTN;
  for (int i = t; i < SORTN; i += 1024) {
    u64 v = 0;
    if ((u32)i < T) {
      int seg = 0;
      while (seg < NSEG - 1 && (u32)i >= pref[seg + 1]) ++seg;
      v = glist[((size_t)(b * NSEG + seg)) * GSEGCAP + ((u32)i - pref[seg])];
    }
    s[i] = v;
  }
  __syncthreads();
  for (int k = 2; k <= SORTN; k <<= 1) {
    for (int j = k >> 1; j > 0; j >>= 1) {
      for (int p = t; p < SORTN / 2; p += 1024) {
        int i = ((p & ~(j - 1)) << 1) | (p & (j - 1));
        cmpswap_desc(s, i, i | j, (i & k) == 0);
      }
      __syncthreads();
    }
  }
  for (int i = t; i < K_NMS; i += 1024) sorted[(size_t)b * K_NMS + i] = s[i];
}

// ---------------------------------------------------------------------------
// Kernel 5: decode the 2048 selected candidates (reference fp32 math exactly).
// ---------------------------------------------------------------------------
__global__ __launch_bounds__(256) void k_decode(const u64* __restrict__ sorted,
                                                const float* __restrict__ props,
                                                const float* __restrict__ regs,
                                                const int* __restrict__ pH,
                                                const int* __restrict__ pW,
                                                float4* __restrict__ raw4,
                                                float4* __restrict__ off4,
                                                float* __restrict__ area,
                                                float* __restrict__ scoref,
                                                int* __restrict__ labeli,
                                                int* __restrict__ flati) {
#pragma clang fp contract(off)
  int t = blockIdx.x * 256 + threadIdx.x;  // 0 .. B*K-1
  int b = t >> 11;
  u64 key = sorted[t];
  if (key == 0ull) {
    raw4[t] = make_float4(0.f, 0.f, 0.f, 0.f);
    off4[t] = make_float4(0.f, 0.f, 0.f, 0.f);
    area[t] = 0.f; scoref[t] = -1.0f; labeli[t] = 0; flati[t] = 0;
    return;
  }
  float Hf = (float)pH[0];
  float Wf = (float)pW[0];
  float offc = fmaxf(Hf, Wf) + 1.0f;  // 1334

  u32 flat = ~(u32)(key & 0xFFFFFFFFull);
  float sc = __uint_as_float((u32)(key >> 32));
  int n = (int)(flat / NCLS);
  int c = (int)(flat - (u32)n * NCLS);

  float4 p = ((const float4*)props)[b * N_ROI + n];
  const float4 dl = *(const float4*)(regs + ((size_t)(b * N_ROI + n)) * (NCLS * 4) + c * 4);

  float mr = fabsf(logf(16.0f / 1000.0f));
  float dx = dl.x * 0.1f;
  float dy = dl.y * 0.1f;
  float dw = fminf(fmaxf(dl.z * 0.2f, -mr), mr);
  float dh = fminf(fmaxf(dl.w * 0.2f, -mr), mr);

  float px = (p.x + p.z) * 0.5f;
  float py = (p.y + p.w) * 0.5f;
  float pw = p.z - p.x;
  float ph = p.w - p.y;

  float tx = pw * dx; float gx = px + tx;
  float ty = ph * dy; float gy = py + ty;
  float gw = pw * expf(dw);
  float gh = ph * expf(dh);
  float hx = gw * 0.5f, hy = gh * 0.5f;

  float x1 = fminf(fmaxf(gx - hx, 0.0f), Wf);
  float y1 = fminf(fmaxf(gy - hy, 0.0f), Hf);
  float x2 = fminf(fmaxf(gx + hx, 0.0f), Wf);
  float y2 = fminf(fmaxf(gy + hy, 0.0f), Hf);

  raw4[t] = make_float4(x1, y1, x2, y2);

  float off = (float)c * offc;
  float ox1 = x1 + off, oy1 = y1 + off, ox2 = x2 + off, oy2 = y2 + off;
  off4[t] = make_float4(ox1, oy1, ox2, oy2);
  area[t] = fmaxf(ox2 - ox1, 0.0f) * fmaxf(oy2 - oy1, 0.0f);
  scoref[t] = sc;
  labeli[t] = c;
  flati[t] = (int)flat;
}

// ---------------------------------------------------------------------------
// Kernel 6: suppression bitmask. Row i: bit j set iff (j>i) && IoU(i,j)>0.5.
// ---------------------------------------------------------------------------
__global__ __launch_bounds__(256) void k_mask(const float4* __restrict__ off4,
                                              const float* __restrict__ area,
                                              u64* __restrict__ masks) {
#pragma clang fp contract(off)
  int wave = threadIdx.x >> 6, lane = threadIdx.x & 63;
  int R = blockIdx.x * 4 + wave;  // 0 .. B*K-1
  int b = R >> 11, i = R & (K_NMS - 1);
  const float4* bb = off4 + (size_t)b * K_NMS;
  const float* aa = area + (size_t)b * K_NMS;
  float4 bi = bb[i];
  float ai = aa[i];
  u64 my = 0;
  for (int w = 0; w < 32; ++w) {
    int j = (w << 6) + lane;
    float4 bj = bb[j];
    float lx = fmaxf(bi.x, bj.x);
    float ly = fmaxf(bi.y, bj.y);
    float rx = fminf(bi.z, bj.z);
    float ry = fminf(bi.w, bj.w);
    float ww = fmaxf(rx - lx, 0.0f);
    float hh = fmaxf(ry - ly, 0.0f);
    float inter = ww * hh;
    float uni = (ai + aa[j]) - inter;
    float iou = inter / fmaxf(uni, 1e-6f);
    bool sup = (j > i) && (iou > THR_IOU);
    u64 word = __ballot(sup);
    if (lane == w) my = word;
  }
  if (lane < 32) masks[((size_t)R << 5) + lane] = my;
}

// ---------------------------------------------------------------------------
// Kernel 7: serial greedy scan (one wave per image) + top-100 output.
// 16-deep prefetch in NAMED registers; mask buffer has 16-row tail pad.
// ---------------------------------------------------------------------------
__global__ __launch_bounds__(64) void k_scanout(const u64* __restrict__ masks,
                                                const float* __restrict__ scoref,
                                                const float4* __restrict__ raw4,
                                                const int* __restrict__ labeli,
                                                const int* __restrict__ flati,
                                                float* __restrict__ out) {
  int b = blockIdx.x;
  int lane = threadIdx.x;

  u64 kw = 0;
  for (int w = 0; w < 32; ++w) {
    bool pred = scoref[(size_t)b * K_NMS + (w << 6) + lane] > 0.0f;
    u64 word = __ballot(pred);
    if (lane == w) kw = word;
  }

  const u64* mrow = masks + ((size_t)b << 16);  // b * 2048 * 32
  bool act = lane < 32;

#define LDROW(r) (act ? mrow[((size_t)(r) << 5) + lane] : 0ull)

  u64 q0 = LDROW(0), q1 = LDROW(1), q2 = LDROW(2), q3 = LDROW(3);
  u64 q4 = LDROW(4), q5 = LDROW(5), q6 = LDROW(6), q7 = LDROW(7);
  u64 q8 = LDROW(8), q9 = LDROW(9), q10 = LDROW(10), q11 = LDROW(11);
  u64 q12 = LDROW(12), q13 = LDROW(13), q14 = LDROW(14), q15 = LDROW(15);

#define STEP(d, qv)                                   \
  {                                                   \
    int i = ii + (d);                                 \
    u64 cm = qv;                                      \
    qv = LDROW(i + 16); /* pad rows make this safe */ \
    u64 kwi = __shfl(kw, i >> 6);                     \
    if ((kwi >> (i & 63)) & 1ull) kw &= ~cm;          \
  }

  for (int ii = 0; ii < K_NMS; ii += 16) {
    STEP(0, q0)  STEP(1, q1)  STEP(2, q2)  STEP(3, q3)
    STEP(4, q4)  STEP(5, q5)  STEP(6, q6)  STEP(7, q7)
    STEP(8, q8)  STEP(9, q9)  STEP(10, q10) STEP(11, q11)
    STEP(12, q12) STEP(13, q13) STEP(14, q14) STEP(15, q15)
  }
#undef STEP
#undef LDROW

  int pc = (lane < 32) ? __popcll(kw) : 0;
  int pre = pc;
  for (int o = 1; o < 64; o <<= 1) {
    int v = __shfl_up(pre, o);
    if (lane >= o) pre += v;
  }
  int excl = pre - pc;
  int total = __shfl(pre, 63);

  float* ob = out;                              // [B,100,4]
  float* os = out + B_IMG * MAXOUT * 4;         // [B,100]
  float* ol = os + B_IMG * MAXOUT;              // [B,100]
  float* oi = ol + B_IMG * MAXOUT;              // [B,100]

  if (lane < 32) {
    u64 w = kw;
    int r = excl;
    while (w) {
      int bit = __ffsll((long long)w) - 1;
      w &= w - 1;
      if (r < MAXOUT) {
        int j = (lane << 6) + bit;
        size_t g = (size_t)b * K_NMS + j;
        float4 bx = raw4[g];
        int o = b * MAXOUT + r;
        ob[o * 4 + 0] = bx.x; ob[o * 4 + 1] = bx.y;
        ob[o * 4 + 2] = bx.z; ob[o * 4 + 3] = bx.w;
        os[o] = scoref[g];
        ol[o] = (float)labeli[g];
        oi[o] = (float)flati[g];
      }
      ++r;
    }
  }
  for (int r = total + lane; r < MAXOUT; r += 64) {
    int o = b * MAXOUT + r;
    ob[o * 4 + 0] = 0.f; ob[o * 4 + 1] = 0.f; ob[o * 4 + 2] = 0.f; ob[o * 4 + 3] = 0.f;
    os[o] = 0.f;
    ol[o] = -1.0f;
    oi[o] = -1.0f;
  }
}

// ---------------------------------------------------------------------------
extern "C" void kernel_launch(void* const* d_in, const int* in_sizes, int n_in,
                              void* d_out, int out_size, void* d_ws, size_t ws_size,
                              hipStream_t stream) {
  const float* cls = (const float*)d_in[0];
  const float* regs = (const float*)d_in[1];
  const float* props = (const float*)d_in[2];
  const int* pH = (const int*)d_in[3];
  const int* pW = (const int*)d_in[4];

  char* ws = (char*)d_ws;
  size_t o = 0;
  u32* hist = (u32*)(ws + o); o += (size_t)B_IMG * NBIN * sizeof(u32);    // 64 KB
  u32* gcnt = (u32*)(ws + o); o += (size_t)B_IMG * NSEG * sizeof(u32);    // 256 B
  size_t zero_bytes = o;  // hist + gcnt zeroed each call
  u32* cut = (u32*)(ws + o); o += 256;
  u64* glist = (u64*)(ws + o); o += (size_t)B_IMG * NSEG * GSEGCAP * sizeof(u64);
  u64* sorted = (u64*)(ws + o); o += (size_t)B_IMG * K_NMS * sizeof(u64);
  float4* raw4 = (float4*)(ws + o); o += (size_t)B_IMG * K_NMS * sizeof(float4);
  float4* off4 = (float4*)(ws + o); o += (size_t)B_IMG * K_NMS * sizeof(float4);
  float* area = (float*)(ws + o); o += (size_t)B_IMG * K_NMS * sizeof(float);
  float* scoref = (float*)(ws + o); o += (size_t)B_IMG * K_NMS * sizeof(float);
  int* labeli = (int*)(ws + o); o += (size_t)B_IMG * K_NMS * sizeof(int);
  int* flati = (int*)(ws + o); o += (size_t)B_IMG * K_NMS * sizeof(int);
  u64* masks = (u64*)(ws + o); o += (size_t)B_IMG * K_NMS * 32 * sizeof(u64);
  o += 16 * 32 * sizeof(u64);  // 4 KB pad: scanout tail prefetch reads 16 rows past end

  hipMemsetAsync(hist, 0, zero_bytes, stream);
  k_hist<<<B_IMG * N_ROI / 16, 1024, 0, stream>>>(cls, hist);
  k_cutoff<<<B_IMG, 1024, 0, stream>>>(hist, cut);
  k_gather<<<B_IMG * N_ROI / 16, 1024, 0, stream>>>(cls, cut, gcnt, glist);
  k_sort<<<B_IMG, 1024, 0, stream>>>(gcnt, glist, sorted);
  k_decode<<<B_IMG * K_NMS / 256, 256, 0, stream>>>(sorted, props, regs, pH, pW,
                                                    raw4, off4, area, scoref, labeli, flati);
  k_mask<<<B_IMG * K_NMS / 4, 256, 0, stream>>>(off4, area, masks);
  k_scanout<<<B_IMG, 64, 0, stream>>>(masks, scoref, raw4, labeli, flati, (float*)d_out);
}

// Round 4
// 210.396 us; speedup vs baseline: 5.3503x; 1.3205x over previous
//
#include <hip/hip_runtime.h>
#include <cstdint>
#include <cstddef>

#pragma clang fp contract(off)

typedef unsigned long long u64;
typedef unsigned int u32;

#define B_IMG 4
#define N_ROI 8192
#define NCLS 80
#define NCOL 81
#define K_NMS 2048
#define MAXOUT 100
#define THR_SCORE 0.05f
#define THR_IOU 0.5f

#define NBIN 4096
#define BIN_OFF 62771u  // (0x3D4CCCCD >> 14): bin of smallest float > 0.05f
#define NSEG 16
#define GSEGCAP 512
#define SORTN 4096

// ---------------------------------------------------------------------------
// Shared softmax: MUST be bit-identical between k_hist and k_gather (it is:
// same inline function, same reduction order, IEEE ops, contract off).
// ---------------------------------------------------------------------------
__device__ __forceinline__ void softmax_row(const float* __restrict__ row, int lane,
                                            float& s0, float& s1) {
  float v0 = row[lane];
  float v1 = (lane < NCOL - 64) ? row[64 + lane] : -1e38f;
  float m = fmaxf(v0, v1);
  for (int o = 32; o; o >>= 1) m = fmaxf(m, __shfl_xor(m, o));
  float e0 = expf(v0 - m);
  float e1 = (lane < NCOL - 64) ? expf(v1 - m) : 0.0f;
  float s = e0 + e1;
  for (int o = 32; o; o >>= 1) s += __shfl_xor(s, o);
  s0 = e0 / s;
  s1 = e1 / s;
}

// ---------------------------------------------------------------------------
// Kernel 1: per-image 4096-bin histogram of candidate score keys.
// ---------------------------------------------------------------------------
__global__ __launch_bounds__(1024) void k_hist(const float* __restrict__ cls,
                                               u32* __restrict__ hist) {
#pragma clang fp contract(off)
  __shared__ u32 lh[NBIN];
  int t = threadIdx.x;
  for (int i = t; i < NBIN; i += 1024) lh[i] = 0;
  __syncthreads();
  int wv = t >> 6, lane = t & 63;
  int wid = blockIdx.x * 16 + wv;  // 16 divides 8192 -> block within one image
  int b = wid >> 13;
  float s0, s1;
  softmax_row(cls + (size_t)wid * NCOL, lane, s0, s1);
  if (s0 > THR_SCORE) atomicAdd(&lh[(__float_as_uint(s0) >> 14) - BIN_OFF], 1u);
  if (lane < 16 && s1 > THR_SCORE) atomicAdd(&lh[(__float_as_uint(s1) >> 14) - BIN_OFF], 1u);
  __syncthreads();
  u32* gh = hist + (size_t)b * NBIN;
  for (int i = t; i < NBIN; i += 1024) {
    u32 c = lh[i];
    if (c) atomicAdd(&gh[i], c);
  }
}

// ---------------------------------------------------------------------------
// Kernel 2: per image, find largest bin c* with suffix_count(c*) >= 2048.
// ---------------------------------------------------------------------------
__global__ __launch_bounds__(1024) void k_cutoff(const u32* __restrict__ hist,
                                                 u32* __restrict__ cut) {
  __shared__ u32 wsum[16];
  __shared__ int best;
  int b = blockIdx.x, t = threadIdx.x;
  const u32* gh = hist + (size_t)b * NBIN;
  u32 v0 = gh[t * 4 + 0], v1 = gh[t * 4 + 1], v2 = gh[t * 4 + 2], v3 = gh[t * 4 + 3];
  u32 my = v0 + v1 + v2 + v3;
  int lane = t & 63, wv = t >> 6;
  u32 inc = my;
  for (int o = 1; o < 64; o <<= 1) {
    u32 x = __shfl_up(inc, o);
    if (lane >= o) inc += x;
  }
  if (lane == 63) wsum[wv] = inc;
  if (t == 0) best = 0;
  __syncthreads();
  u32 wpre = 0;
  for (int i = 0; i < wv; ++i) wpre += wsum[i];
  u32 total = 0;
  for (int i = 0; i < 16; ++i) total += wsum[i];
  u32 excl = wpre + (inc - my);  // prefix(bin t*4)
  if (total >= K_NMS) {
    u32 lim = total - K_NMS;
    u32 p = excl;
    int cand = -1;
    if (p <= lim) cand = t * 4 + 0; p += v0;
    if (p <= lim) cand = t * 4 + 1; p += v1;
    if (p <= lim) cand = t * 4 + 2; p += v2;
    if (p <= lim) cand = t * 4 + 3; p += v3;
    if (cand >= 0) atomicMax(&best, cand);
  }
  __syncthreads();
  if (t == 0) cut[b] = (total >= K_NMS) ? (u32)best : 0u;
}

// ---------------------------------------------------------------------------
// Kernel 3: recompute softmax, append items with bin >= cut[b] to 16 segments
// per image. Block-aggregated atomics.
// ---------------------------------------------------------------------------
__global__ __launch_bounds__(1024) void k_gather(const float* __restrict__ cls,
                                                 const u32* __restrict__ cut,
                                                 u32* __restrict__ gcnt,
                                                 u64* __restrict__ glist) {
#pragma clang fp contract(off)
  __shared__ u32 wbase[16];
  __shared__ u32 blkcnt;
  __shared__ u32 gbase;
  int t = threadIdx.x, wv = t >> 6, lane = t & 63;
  int wid = blockIdx.x * 16 + wv;
  int b = wid >> 13;
  int n = wid & (N_ROI - 1);
  if (t == 0) blkcnt = 0;
  __syncthreads();
  float s0, s1;
  softmax_row(cls + (size_t)wid * NCOL, lane, s0, s1);
  u32 c = cut[b];
  bool c0 = (s0 > THR_SCORE) && (((__float_as_uint(s0) >> 14) - BIN_OFF) >= c);
  bool c1 = (lane < 16) && (s1 > THR_SCORE) && (((__float_as_uint(s1) >> 14) - BIN_OFF) >= c);
  u64 b0 = __ballot(c0), b1 = __ballot(c1);
  int cnt = __popcll(b0) + __popcll(b1);
  if (lane == 0) wbase[wv] = atomicAdd(&blkcnt, (u32)cnt);
  __syncthreads();
  int seg = blockIdx.x & (NSEG - 1);  // 512 blocks/image -> 32 blocks/segment
  if (t == 0) gbase = atomicAdd(&gcnt[b * NSEG + seg], blkcnt);
  __syncthreads();
  u32 base = gbase + wbase[wv];
  u64 lm = (1ull << lane) - 1ull;
  u64* seglist = glist + ((size_t)(b * NSEG + seg)) * GSEGCAP;
  if (c0) {
    u32 pos = base + (u32)__popcll(b0 & lm);
    if (pos < GSEGCAP) {
      u32 flat = (u32)(n * NCLS + lane);
      seglist[pos] = ((u64)__float_as_uint(s0) << 32) | (u32)(~flat);
    }
  }
  if (c1) {
    u32 pos = base + (u32)__popcll(b0) + (u32)__popcll(b1 & lm);
    if (pos < GSEGCAP) {
      u32 flat = (u32)(n * NCLS + 64 + lane);
      seglist[pos] = ((u64)__float_as_uint(s1) << 32) | (u32)(~flat);
    }
  }
}

// ---------------------------------------------------------------------------
// Kernel 4: per-image bitonic sort (desc) of <=4096 gathered keys in LDS.
// ---------------------------------------------------------------------------
__device__ inline void cmpswap_desc(u64* s, int i, int p, bool desc) {
  u64 a = s[i], b = s[p];
  if ((a < b) == desc) { s[i] = b; s[p] = a; }
}

__global__ __launch_bounds__(1024) void k_sort(const u32* __restrict__ gcnt,
                                               const u64* __restrict__ glist,
                                               u64* __restrict__ sorted) {
  __shared__ u64 s[SORTN];
  __shared__ u32 pref[NSEG + 1];
  int b = blockIdx.x, t = threadIdx.x;
  if (t == 0) {
    u32 p = 0;
    for (int i = 0; i < NSEG; ++i) {
      pref[i] = p;
      u32 cc = gcnt[b * NSEG + i];
      if (cc > GSEGCAP) cc = GSEGCAP;
      p += cc;
    }
    pref[NSEG] = p;
  }
  __syncthreads();
  u32 T = pref[NSEG];
  if (T > SORTN) T = SORTN;
  for (int i = t; i < SORTN; i += 1024) {
    u64 v = 0;
    if ((u32)i < T) {
      int seg = 0;
      while (seg < NSEG - 1 && (u32)i >= pref[seg + 1]) ++seg;
      v = glist[((size_t)(b * NSEG + seg)) * GSEGCAP + ((u32)i - pref[seg])];
    }
    s[i] = v;
  }
  __syncthreads();
  for (int k = 2; k <= SORTN; k <<= 1) {
    for (int j = k >> 1; j > 0; j >>= 1) {
      for (int p = t; p < SORTN / 2; p += 1024) {
        int i = ((p & ~(j - 1)) << 1) | (p & (j - 1));
        cmpswap_desc(s, i, i | j, (i & k) == 0);
      }
      __syncthreads();
    }
  }
  for (int i = t; i < K_NMS; i += 1024) sorted[(size_t)b * K_NMS + i] = s[i];
}

// ---------------------------------------------------------------------------
// Kernel 5: decode the 2048 selected candidates (reference fp32 math exactly).
// ---------------------------------------------------------------------------
__global__ __launch_bounds__(256) void k_decode(const u64* __restrict__ sorted,
                                                const float* __restrict__ props,
                                                const float* __restrict__ regs,
                                                const int* __restrict__ pH,
                                                const int* __restrict__ pW,
                                                float4* __restrict__ raw4,
                                                float4* __restrict__ off4,
                                                float* __restrict__ area,
                                                float* __restrict__ scoref,
                                                int* __restrict__ labeli,
                                                int* __restrict__ flati) {
#pragma clang fp contract(off)
  int t = blockIdx.x * 256 + threadIdx.x;  // 0 .. B*K-1
  int b = t >> 11;
  u64 key = sorted[t];
  if (key == 0ull) {
    raw4[t] = make_float4(0.f, 0.f, 0.f, 0.f);
    off4[t] = make_float4(0.f, 0.f, 0.f, 0.f);
    area[t] = 0.f; scoref[t] = -1.0f; labeli[t] = 0; flati[t] = 0;
    return;
  }
  float Hf = (float)pH[0];
  float Wf = (float)pW[0];
  float offc = fmaxf(Hf, Wf) + 1.0f;  // 1334

  u32 flat = ~(u32)(key & 0xFFFFFFFFull);
  float sc = __uint_as_float((u32)(key >> 32));
  int n = (int)(flat / NCLS);
  int c = (int)(flat - (u32)n * NCLS);

  float4 p = ((const float4*)props)[b * N_ROI + n];
  const float4 dl = *(const float4*)(regs + ((size_t)(b * N_ROI + n)) * (NCLS * 4) + c * 4);

  float mr = fabsf(logf(16.0f / 1000.0f));
  float dx = dl.x * 0.1f;
  float dy = dl.y * 0.1f;
  float dw = fminf(fmaxf(dl.z * 0.2f, -mr), mr);
  float dh = fminf(fmaxf(dl.w * 0.2f, -mr), mr);

  float px = (p.x + p.z) * 0.5f;
  float py = (p.y + p.w) * 0.5f;
  float pw = p.z - p.x;
  float ph = p.w - p.y;

  float tx = pw * dx; float gx = px + tx;
  float ty = ph * dy; float gy = py + ty;
  float gw = pw * expf(dw);
  float gh = ph * expf(dh);
  float hx = gw * 0.5f, hy = gh * 0.5f;

  float x1 = fminf(fmaxf(gx - hx, 0.0f), Wf);
  float y1 = fminf(fmaxf(gy - hy, 0.0f), Hf);
  float x2 = fminf(fmaxf(gx + hx, 0.0f), Wf);
  float y2 = fminf(fmaxf(gy + hy, 0.0f), Hf);

  raw4[t] = make_float4(x1, y1, x2, y2);

  float off = (float)c * offc;
  float ox1 = x1 + off, oy1 = y1 + off, ox2 = x2 + off, oy2 = y2 + off;
  off4[t] = make_float4(ox1, oy1, ox2, oy2);
  area[t] = fmaxf(ox2 - ox1, 0.0f) * fmaxf(oy2 - oy1, 0.0f);
  scoref[t] = sc;
  labeli[t] = c;
  flati[t] = (int)flat;
}

// ---------------------------------------------------------------------------
// Kernel 6: suppression bitmask. Row i: bit j set iff (j>i) && IoU(i,j)>0.5.
// ---------------------------------------------------------------------------
__global__ __launch_bounds__(256) void k_mask(const float4* __restrict__ off4,
                                              const float* __restrict__ area,
                                              u64* __restrict__ masks) {
#pragma clang fp contract(off)
  int wave = threadIdx.x >> 6, lane = threadIdx.x & 63;
  int R = blockIdx.x * 4 + wave;  // 0 .. B*K-1
  int b = R >> 11, i = R & (K_NMS - 1);
  const float4* bb = off4 + (size_t)b * K_NMS;
  const float* aa = area + (size_t)b * K_NMS;
  float4 bi = bb[i];
  float ai = aa[i];
  u64 my = 0;
  for (int w = 0; w < 32; ++w) {
    int j = (w << 6) + lane;
    float4 bj = bb[j];
    float lx = fmaxf(bi.x, bj.x);
    float ly = fmaxf(bi.y, bj.y);
    float rx = fminf(bi.z, bj.z);
    float ry = fminf(bi.w, bj.w);
    float ww = fmaxf(rx - lx, 0.0f);
    float hh = fmaxf(ry - ly, 0.0f);
    float inter = ww * hh;
    float uni = (ai + aa[j]) - inter;
    float iou = inter / fmaxf(uni, 1e-6f);
    bool sup = (j > i) && (iou > THR_IOU);
    u64 word = __ballot(sup);
    if (lane == w) my = word;
  }
  if (lane < 32) masks[((size_t)R << 5) + lane] = my;
}

// ---------------------------------------------------------------------------
// Kernel 7: serial greedy scan, chunk-broadcast form. One wave per image.
// - __launch_bounds__(64,1): unlock VGPR budget so 32 named u64 prefetch
//   registers (rows i..i+31) actually live in VGPRs (rule #20 + G6).
// - Serial chain is 3 VALU ops: the per-row shuffle (diag = row's word c)
//   operates on loaded data only, NOT on the running keep state, so it can
//   be scheduled 32 rows ahead of use.
// ---------------------------------------------------------------------------
__global__ __launch_bounds__(64, 1) void k_scanout(const u64* __restrict__ masks,
                                                   const float* __restrict__ scoref,
                                                   const float4* __restrict__ raw4,
                                                   const int* __restrict__ labeli,
                                                   const int* __restrict__ flati,
                                                   float* __restrict__ out) {
  int b = blockIdx.x;
  int lane = threadIdx.x;

  // keep init: valid = score > 0; lane w (w<32) owns keep word w
  u64 kw = 0;
  for (int w = 0; w < 32; ++w) {
    bool pred = scoref[(size_t)b * K_NMS + (w << 6) + lane] > 0.0f;
    u64 word = __ballot(pred);
    if (lane == w) kw = word;
  }

  const u64* mrow = masks + ((size_t)b << 16);  // b * 2048 * 32
  int myw = lane & 31;                          // all 64 lanes load (upper dup)

#define LDROW(r) mrow[((size_t)(r) << 5) + myw]

  u64 q0 = LDROW(0), q1 = LDROW(1), q2 = LDROW(2), q3 = LDROW(3);
  u64 q4 = LDROW(4), q5 = LDROW(5), q6 = LDROW(6), q7 = LDROW(7);
  u64 q8 = LDROW(8), q9 = LDROW(9), q10 = LDROW(10), q11 = LDROW(11);
  u64 q12 = LDROW(12), q13 = LDROW(13), q14 = LDROW(14), q15 = LDROW(15);
  u64 q16 = LDROW(16), q17 = LDROW(17), q18 = LDROW(18), q19 = LDROW(19);
  u64 q20 = LDROW(20), q21 = LDROW(21), q22 = LDROW(22), q23 = LDROW(23);
  u64 q24 = LDROW(24), q25 = LDROW(25), q26 = LDROW(26), q27 = LDROW(27);
  u64 q28 = LDROW(28), q29 = LDROW(29), q30 = LDROW(30), q31 = LDROW(31);

  // STEPX(dd, qv): process row i = base+dd; qv holds its mask word; reload
  // qv with row i+32 (pad rows keep the tail in-bounds).
#define STEPX(dd, qv)                                  \
  {                                                    \
    u64 cm = qv;                                       \
    qv = LDROW(base + (dd) + 32);                      \
    u64 diag = __shfl(cm, c);                          \
    u64 on = (u64)0 - ((kcur >> (dd)) & 1ull);         \
    kw &= ~(cm & on);                                  \
    kcur &= ~(diag & on);                              \
  }

  for (int c = 0; c < 32; ++c) {
    int base = c << 6;
    u64 kcur = __shfl(kw, c);  // replicate keep word c into all lanes
    STEPX(0, q0)   STEPX(1, q1)   STEPX(2, q2)   STEPX(3, q3)
    STEPX(4, q4)   STEPX(5, q5)   STEPX(6, q6)   STEPX(7, q7)
    STEPX(8, q8)   STEPX(9, q9)   STEPX(10, q10) STEPX(11, q11)
    STEPX(12, q12) STEPX(13, q13) STEPX(14, q14) STEPX(15, q15)
    STEPX(16, q16) STEPX(17, q17) STEPX(18, q18) STEPX(19, q19)
    STEPX(20, q20) STEPX(21, q21) STEPX(22, q22) STEPX(23, q23)
    STEPX(24, q24) STEPX(25, q25) STEPX(26, q26) STEPX(27, q27)
    STEPX(28, q28) STEPX(29, q29) STEPX(30, q30) STEPX(31, q31)
    STEPX(32, q0)  STEPX(33, q1)  STEPX(34, q2)  STEPX(35, q3)
    STEPX(36, q4)  STEPX(37, q5)  STEPX(38, q6)  STEPX(39, q7)
    STEPX(40, q8)  STEPX(41, q9)  STEPX(42, q10) STEPX(43, q11)
    STEPX(44, q12) STEPX(45, q13) STEPX(46, q14) STEPX(47, q15)
    STEPX(48, q16) STEPX(49, q17) STEPX(50, q18) STEPX(51, q19)
    STEPX(52, q20) STEPX(53, q21) STEPX(54, q22) STEPX(55, q23)
    STEPX(56, q24) STEPX(57, q25) STEPX(58, q26) STEPX(59, q27)
    STEPX(60, q28) STEPX(61, q29) STEPX(62, q30) STEPX(63, q31)
  }
#undef STEPX
#undef LDROW

  int pc = (lane < 32) ? __popcll(kw) : 0;
  int pre = pc;
  for (int o = 1; o < 64; o <<= 1) {
    int v = __shfl_up(pre, o);
    if (lane >= o) pre += v;
  }
  int excl = pre - pc;
  int total = __shfl(pre, 63);

  float* ob = out;                              // [B,100,4]
  float* os = out + B_IMG * MAXOUT * 4;         // [B,100]
  float* ol = os + B_IMG * MAXOUT;              // [B,100]
  float* oi = ol + B_IMG * MAXOUT;              // [B,100]

  if (lane < 32) {
    u64 w = kw;
    int r = excl;
    while (w) {
      int bit = __ffsll((long long)w) - 1;
      w &= w - 1;
      if (r < MAXOUT) {
        int j = (lane << 6) + bit;
        size_t g = (size_t)b * K_NMS + j;
        float4 bx = raw4[g];
        int o = b * MAXOUT + r;
        ob[o * 4 + 0] = bx.x; ob[o * 4 + 1] = bx.y;
        ob[o * 4 + 2] = bx.z; ob[o * 4 + 3] = bx.w;
        os[o] = scoref[g];
        ol[o] = (float)labeli[g];
        oi[o] = (float)flati[g];
      }
      ++r;
    }
  }
  for (int r = total + lane; r < MAXOUT; r += 64) {
    int o = b * MAXOUT + r;
    ob[o * 4 + 0] = 0.f; ob[o * 4 + 1] = 0.f; ob[o * 4 + 2] = 0.f; ob[o * 4 + 3] = 0.f;
    os[o] = 0.f;
    ol[o] = -1.0f;
    oi[o] = -1.0f;
  }
}

// ---------------------------------------------------------------------------
extern "C" void kernel_launch(void* const* d_in, const int* in_sizes, int n_in,
                              void* d_out, int out_size, void* d_ws, size_t ws_size,
                              hipStream_t stream) {
  const float* cls = (const float*)d_in[0];
  const float* regs = (const float*)d_in[1];
  const float* props = (const float*)d_in[2];
  const int* pH = (const int*)d_in[3];
  const int* pW = (const int*)d_in[4];

  char* ws = (char*)d_ws;
  size_t o = 0;
  u32* hist = (u32*)(ws + o); o += (size_t)B_IMG * NBIN * sizeof(u32);    // 64 KB
  u32* gcnt = (u32*)(ws + o); o += (size_t)B_IMG * NSEG * sizeof(u32);    // 256 B
  size_t zero_bytes = o;  // hist + gcnt zeroed each call
  u32* cut = (u32*)(ws + o); o += 256;
  u64* glist = (u64*)(ws + o); o += (size_t)B_IMG * NSEG * GSEGCAP * sizeof(u64);
  u64* sorted = (u64*)(ws + o); o += (size_t)B_IMG * K_NMS * sizeof(u64);
  float4* raw4 = (float4*)(ws + o); o += (size_t)B_IMG * K_NMS * sizeof(float4);
  float4* off4 = (float4*)(ws + o); o += (size_t)B_IMG * K_NMS * sizeof(float4);
  float* area = (float*)(ws + o); o += (size_t)B_IMG * K_NMS * sizeof(float);
  float* scoref = (float*)(ws + o); o += (size_t)B_IMG * K_NMS * sizeof(float);
  int* labeli = (int*)(ws + o); o += (size_t)B_IMG * K_NMS * sizeof(int);
  int* flati = (int*)(ws + o); o += (size_t)B_IMG * K_NMS * sizeof(int);
  u64* masks = (u64*)(ws + o); o += (size_t)B_IMG * K_NMS * 32 * sizeof(u64);
  o += 32 * 32 * sizeof(u64);  // 8 KB pad: scanout tail prefetch reads 32 rows past end

  hipMemsetAsync(hist, 0, zero_bytes, stream);
  k_hist<<<B_IMG * N_ROI / 16, 1024, 0, stream>>>(cls, hist);
  k_cutoff<<<B_IMG, 1024, 0, stream>>>(hist, cut);
  k_gather<<<B_IMG * N_ROI / 16, 1024, 0, stream>>>(cls, cut, gcnt, glist);
  k_sort<<<B_IMG, 1024, 0, stream>>>(gcnt, glist, sorted);
  k_decode<<<B_IMG * K_NMS / 256, 256, 0, stream>>>(sorted, props, regs, pH, pW,
                                                    raw4, off4, area, scoref, labeli, flati);
  k_mask<<<B_IMG * K_NMS / 4, 256, 0, stream>>>(off4, area, masks);
  k_scanout<<<B_IMG, 64, 0, stream>>>(masks, scoref, raw4, labeli, flati, (float*)d_out);
}

// Round 5
// 190.076 us; speedup vs baseline: 5.9223x; 1.1069x over previous
//
#include <hip/hip_runtime.h>
#include <cstdint>
#include <cstddef>

#pragma clang fp contract(off)

typedef unsigned long long u64;
typedef unsigned int u32;

#define B_IMG 4
#define N_ROI 8192
#define NCLS 80
#define NCOL 81
#define K_NMS 2048
#define MAXOUT 100
#define THR_SCORE 0.05f
#define THR_IOU 0.5f

#define NBIN 4096
#define BIN_OFF 62771u  // (0x3D4CCCCD >> 14): bin of smallest float > 0.05f
#define NSEG 16
#define GSEGCAP 512
#define SORTN 4096

// ---------------------------------------------------------------------------
// Shared softmax: MUST be bit-identical between k_hist and k_gather (it is:
// same inline function, same reduction order, IEEE ops, contract off).
// ---------------------------------------------------------------------------
__device__ __forceinline__ void softmax_row(const float* __restrict__ row, int lane,
                                            float& s0, float& s1) {
  float v0 = row[lane];
  float v1 = (lane < NCOL - 64) ? row[64 + lane] : -1e38f;
  float m = fmaxf(v0, v1);
  for (int o = 32; o; o >>= 1) m = fmaxf(m, __shfl_xor(m, o));
  float e0 = expf(v0 - m);
  float e1 = (lane < NCOL - 64) ? expf(v1 - m) : 0.0f;
  float s = e0 + e1;
  for (int o = 32; o; o >>= 1) s += __shfl_xor(s, o);
  s0 = e0 / s;
  s1 = e1 / s;
}

// ---------------------------------------------------------------------------
// Kernel 1: per-image 4096-bin histogram of candidate score keys.
// ---------------------------------------------------------------------------
__global__ __launch_bounds__(1024) void k_hist(const float* __restrict__ cls,
                                               u32* __restrict__ hist) {
#pragma clang fp contract(off)
  __shared__ u32 lh[NBIN];
  int t = threadIdx.x;
  for (int i = t; i < NBIN; i += 1024) lh[i] = 0;
  __syncthreads();
  int wv = t >> 6, lane = t & 63;
  int wid = blockIdx.x * 16 + wv;  // 16 divides 8192 -> block within one image
  int b = wid >> 13;
  float s0, s1;
  softmax_row(cls + (size_t)wid * NCOL, lane, s0, s1);
  if (s0 > THR_SCORE) atomicAdd(&lh[(__float_as_uint(s0) >> 14) - BIN_OFF], 1u);
  if (lane < 16 && s1 > THR_SCORE) atomicAdd(&lh[(__float_as_uint(s1) >> 14) - BIN_OFF], 1u);
  __syncthreads();
  u32* gh = hist + (size_t)b * NBIN;
  for (int i = t; i < NBIN; i += 1024) {
    u32 c = lh[i];
    if (c) atomicAdd(&gh[i], c);
  }
}

// ---------------------------------------------------------------------------
// Kernel 2: per image, find largest bin c* with suffix_count(c*) >= 2048.
// ---------------------------------------------------------------------------
__global__ __launch_bounds__(1024) void k_cutoff(const u32* __restrict__ hist,
                                                 u32* __restrict__ cut) {
  __shared__ u32 wsum[16];
  __shared__ int best;
  int b = blockIdx.x, t = threadIdx.x;
  const u32* gh = hist + (size_t)b * NBIN;
  u32 v0 = gh[t * 4 + 0], v1 = gh[t * 4 + 1], v2 = gh[t * 4 + 2], v3 = gh[t * 4 + 3];
  u32 my = v0 + v1 + v2 + v3;
  int lane = t & 63, wv = t >> 6;
  u32 inc = my;
  for (int o = 1; o < 64; o <<= 1) {
    u32 x = __shfl_up(inc, o);
    if (lane >= o) inc += x;
  }
  if (lane == 63) wsum[wv] = inc;
  if (t == 0) best = 0;
  __syncthreads();
  u32 wpre = 0;
  for (int i = 0; i < wv; ++i) wpre += wsum[i];
  u32 total = 0;
  for (int i = 0; i < 16; ++i) total += wsum[i];
  u32 excl = wpre + (inc - my);  // prefix(bin t*4)
  if (total >= K_NMS) {
    u32 lim = total - K_NMS;
    u32 p = excl;
    int cand = -1;
    if (p <= lim) cand = t * 4 + 0; p += v0;
    if (p <= lim) cand = t * 4 + 1; p += v1;
    if (p <= lim) cand = t * 4 + 2; p += v2;
    if (p <= lim) cand = t * 4 + 3; p += v3;
    if (cand >= 0) atomicMax(&best, cand);
  }
  __syncthreads();
  if (t == 0) cut[b] = (total >= K_NMS) ? (u32)best : 0u;
}

// ---------------------------------------------------------------------------
// Kernel 3: recompute softmax, append items with bin >= cut[b] to 16 segments
// per image. Block-aggregated atomics.
// ---------------------------------------------------------------------------
__global__ __launch_bounds__(1024) void k_gather(const float* __restrict__ cls,
                                                 const u32* __restrict__ cut,
                                                 u32* __restrict__ gcnt,
                                                 u64* __restrict__ glist) {
#pragma clang fp contract(off)
  __shared__ u32 wbase[16];
  __shared__ u32 blkcnt;
  __shared__ u32 gbase;
  int t = threadIdx.x, wv = t >> 6, lane = t & 63;
  int wid = blockIdx.x * 16 + wv;
  int b = wid >> 13;
  int n = wid & (N_ROI - 1);
  if (t == 0) blkcnt = 0;
  __syncthreads();
  float s0, s1;
  softmax_row(cls + (size_t)wid * NCOL, lane, s0, s1);
  u32 c = cut[b];
  bool c0 = (s0 > THR_SCORE) && (((__float_as_uint(s0) >> 14) - BIN_OFF) >= c);
  bool c1 = (lane < 16) && (s1 > THR_SCORE) && (((__float_as_uint(s1) >> 14) - BIN_OFF) >= c);
  u64 b0 = __ballot(c0), b1 = __ballot(c1);
  int cnt = __popcll(b0) + __popcll(b1);
  if (lane == 0) wbase[wv] = atomicAdd(&blkcnt, (u32)cnt);
  __syncthreads();
  int seg = blockIdx.x & (NSEG - 1);  // 512 blocks/image -> 32 blocks/segment
  if (t == 0) gbase = atomicAdd(&gcnt[b * NSEG + seg], blkcnt);
  __syncthreads();
  u32 base = gbase + wbase[wv];
  u64 lm = (1ull << lane) - 1ull;
  u64* seglist = glist + ((size_t)(b * NSEG + seg)) * GSEGCAP;
  if (c0) {
    u32 pos = base + (u32)__popcll(b0 & lm);
    if (pos < GSEGCAP) {
      u32 flat = (u32)(n * NCLS + lane);
      seglist[pos] = ((u64)__float_as_uint(s0) << 32) | (u32)(~flat);
    }
  }
  if (c1) {
    u32 pos = base + (u32)__popcll(b0) + (u32)__popcll(b1 & lm);
    if (pos < GSEGCAP) {
      u32 flat = (u32)(n * NCLS + 64 + lane);
      seglist[pos] = ((u64)__float_as_uint(s1) << 32) | (u32)(~flat);
    }
  }
}

// ---------------------------------------------------------------------------
// Kernel 4: per-image bitonic sort (desc) of <=4096 gathered keys in LDS.
// ---------------------------------------------------------------------------
__device__ inline void cmpswap_desc(u64* s, int i, int p, bool desc) {
  u64 a = s[i], b = s[p];
  if ((a < b) == desc) { s[i] = b; s[p] = a; }
}

__global__ __launch_bounds__(1024) void k_sort(const u32* __restrict__ gcnt,
                                               const u64* __restrict__ glist,
                                               u64* __restrict__ sorted) {
  __shared__ u64 s[SORTN];
  __shared__ u32 pref[NSEG + 1];
  int b = blockIdx.x, t = threadIdx.x;
  if (t == 0) {
    u32 p = 0;
    for (int i = 0; i < NSEG; ++i) {
      pref[i] = p;
      u32 cc = gcnt[b * NSEG + i];
      if (cc > GSEGCAP) cc = GSEGCAP;
      p += cc;
    }
    pref[NSEG] = p;
  }
  __syncthreads();
  u32 T = pref[NSEG];
  if (T > SORTN) T = SORTN;
  for (int i = t; i < SORTN; i += 1024) {
    u64 v = 0;
    if ((u32)i < T) {
      int seg = 0;
      while (seg < NSEG - 1 && (u32)i >= pref[seg + 1]) ++seg;
      v = glist[((size_t)(b * NSEG + seg)) * GSEGCAP + ((u32)i - pref[seg])];
    }
    s[i] = v;
  }
  __syncthreads();
  for (int k = 2; k <= SORTN; k <<= 1) {
    for (int j = k >> 1; j > 0; j >>= 1) {
      for (int p = t; p < SORTN / 2; p += 1024) {
        int i = ((p & ~(j - 1)) << 1) | (p & (j - 1));
        cmpswap_desc(s, i, i | j, (i & k) == 0);
      }
      __syncthreads();
    }
  }
  for (int i = t; i < K_NMS; i += 1024) sorted[(size_t)b * K_NMS + i] = s[i];
}

// ---------------------------------------------------------------------------
// Kernel 5: decode the 2048 selected candidates (reference fp32 math exactly).
// ---------------------------------------------------------------------------
__global__ __launch_bounds__(256) void k_decode(const u64* __restrict__ sorted,
                                                const float* __restrict__ props,
                                                const float* __restrict__ regs,
                                                const int* __restrict__ pH,
                                                const int* __restrict__ pW,
                                                float4* __restrict__ raw4,
                                                float4* __restrict__ off4,
                                                float* __restrict__ area,
                                                float* __restrict__ scoref,
                                                int* __restrict__ labeli,
                                                int* __restrict__ flati) {
#pragma clang fp contract(off)
  int t = blockIdx.x * 256 + threadIdx.x;  // 0 .. B*K-1
  int b = t >> 11;
  u64 key = sorted[t];
  if (key == 0ull) {
    raw4[t] = make_float4(0.f, 0.f, 0.f, 0.f);
    off4[t] = make_float4(0.f, 0.f, 0.f, 0.f);
    area[t] = 0.f; scoref[t] = -1.0f; labeli[t] = 0; flati[t] = 0;
    return;
  }
  float Hf = (float)pH[0];
  float Wf = (float)pW[0];
  float offc = fmaxf(Hf, Wf) + 1.0f;  // 1334

  u32 flat = ~(u32)(key & 0xFFFFFFFFull);
  float sc = __uint_as_float((u32)(key >> 32));
  int n = (int)(flat / NCLS);
  int c = (int)(flat - (u32)n * NCLS);

  float4 p = ((const float4*)props)[b * N_ROI + n];
  const float4 dl = *(const float4*)(regs + ((size_t)(b * N_ROI + n)) * (NCLS * 4) + c * 4);

  float mr = fabsf(logf(16.0f / 1000.0f));
  float dx = dl.x * 0.1f;
  float dy = dl.y * 0.1f;
  float dw = fminf(fmaxf(dl.z * 0.2f, -mr), mr);
  float dh = fminf(fmaxf(dl.w * 0.2f, -mr), mr);

  float px = (p.x + p.z) * 0.5f;
  float py = (p.y + p.w) * 0.5f;
  float pw = p.z - p.x;
  float ph = p.w - p.y;

  float tx = pw * dx; float gx = px + tx;
  float ty = ph * dy; float gy = py + ty;
  float gw = pw * expf(dw);
  float gh = ph * expf(dh);
  float hx = gw * 0.5f, hy = gh * 0.5f;

  float x1 = fminf(fmaxf(gx - hx, 0.0f), Wf);
  float y1 = fminf(fmaxf(gy - hy, 0.0f), Hf);
  float x2 = fminf(fmaxf(gx + hx, 0.0f), Wf);
  float y2 = fminf(fmaxf(gy + hy, 0.0f), Hf);

  raw4[t] = make_float4(x1, y1, x2, y2);

  float off = (float)c * offc;
  float ox1 = x1 + off, oy1 = y1 + off, ox2 = x2 + off, oy2 = y2 + off;
  off4[t] = make_float4(ox1, oy1, ox2, oy2);
  area[t] = fmaxf(ox2 - ox1, 0.0f) * fmaxf(oy2 - oy1, 0.0f);
  scoref[t] = sc;
  labeli[t] = c;
  flati[t] = (int)flat;
}

// ---------------------------------------------------------------------------
// Kernel 6: suppression bitmask. Row i: bit j set iff (j>i) && IoU(i,j)>0.5.
// ---------------------------------------------------------------------------
__global__ __launch_bounds__(256) void k_mask(const float4* __restrict__ off4,
                                              const float* __restrict__ area,
                                              u64* __restrict__ masks) {
#pragma clang fp contract(off)
  int wave = threadIdx.x >> 6, lane = threadIdx.x & 63;
  int R = blockIdx.x * 4 + wave;  // 0 .. B*K-1
  int b = R >> 11, i = R & (K_NMS - 1);
  const float4* bb = off4 + (size_t)b * K_NMS;
  const float* aa = area + (size_t)b * K_NMS;
  float4 bi = bb[i];
  float ai = aa[i];
  u64 my = 0;
  for (int w = 0; w < 32; ++w) {
    int j = (w << 6) + lane;
    float4 bj = bb[j];
    float lx = fmaxf(bi.x, bj.x);
    float ly = fmaxf(bi.y, bj.y);
    float rx = fminf(bi.z, bj.z);
    float ry = fminf(bi.w, bj.w);
    float ww = fmaxf(rx - lx, 0.0f);
    float hh = fmaxf(ry - ly, 0.0f);
    float inter = ww * hh;
    float uni = (ai + aa[j]) - inter;
    float iou = inter / fmaxf(uni, 1e-6f);
    bool sup = (j > i) && (iou > THR_IOU);
    u64 word = __ballot(sup);
    if (lane == w) my = word;
  }
  if (lane < 32) masks[((size_t)R << 5) + lane] = my;
}

// ---------------------------------------------------------------------------
// Kernel 7: greedy scan, chunked closure form. One wave per image.
// Per 64-row chunk c:
//   (a) closure: lane i holds row (c*64+i)'s word c ("diag"); the 64-step
//       greedy recurrence runs in WAVE-UNIFORM scalars (readlane broadcasts,
//       d is a compile-time constant under full unroll) -> ~4 cyc/step,
//       no memory op in the chain.
//   (b) apply: supp[w] = OR of kept rows' mask words; 32 independent loads
//       per lane consumed immediately (no cross-iteration liveness -> the
//       scheduler clusters them; they don't depend on (a) so they overlap).
// Equivalent bit-for-bit to the reference fori_loop (mask has only j>i bits).
// ---------------------------------------------------------------------------
__global__ __launch_bounds__(64, 1) void k_scanout(const u64* __restrict__ masks,
                                                   const float* __restrict__ scoref,
                                                   const float4* __restrict__ raw4,
                                                   const int* __restrict__ labeli,
                                                   const int* __restrict__ flati,
                                                   float* __restrict__ out) {
  int b = blockIdx.x;
  int lane = threadIdx.x;

  // keep init: valid = score > 0; lane w (w<32) owns keep word w
  u64 kw = 0;
  for (int w = 0; w < 32; ++w) {
    bool pred = scoref[(size_t)b * K_NMS + (w << 6) + lane] > 0.0f;
    u64 word = __ballot(pred);
    if (lane == w) kw = word;
  }

  const u64* mrow = masks + ((size_t)b << 16);  // b * 2048 * 32
  int myw = lane & 31;
  int half = lane >> 5;

  // diag for chunk c: lane i -> mask[c*64 + i], word c. 1-chunk rotation.
  u64 dnext = mrow[((size_t)lane << 5) + 0];

  for (int c = 0; c < 32; ++c) {
    u64 dcur = dnext;
    if (c < 31) dnext = mrow[((size_t)((c + 1) * 64 + lane) << 5) + (c + 1)];

    // ---- (a) scalar closure of chunk c ----
    u32 dlo = (u32)dcur, dhi = (u32)(dcur >> 32);
    u64 kc = ((u64)(u32)__builtin_amdgcn_readlane((int)(u32)(kw >> 32), c) << 32) |
             (u32)__builtin_amdgcn_readlane((int)(u32)kw, c);
#pragma unroll
    for (int d = 0; d < 64; ++d) {
      u64 dg = ((u64)(u32)__builtin_amdgcn_readlane((int)dhi, d) << 32) |
               (u32)__builtin_amdgcn_readlane((int)dlo, d);
      u64 on = (u64)0 - ((kc >> d) & 1ull);
      kc &= ~(dg & on);
    }

    // ---- (b) apply suppression of kept rows to all 32 words ----
    u32 kb = half ? (u32)(kc >> 32) : (u32)kc;  // rows half*32..half*32+31
    const u64* rb = mrow + (((size_t)(c * 64 + half * 32)) << 5) + myw;
    u64 a0 = 0, a1 = 0, a2 = 0, a3 = 0;
#pragma unroll
    for (int r = 0; r < 32; r += 4) {
      u64 o0 = (u64)0 - (u64)((kb >> (r + 0)) & 1u);
      u64 o1 = (u64)0 - (u64)((kb >> (r + 1)) & 1u);
      u64 o2 = (u64)0 - (u64)((kb >> (r + 2)) & 1u);
      u64 o3 = (u64)0 - (u64)((kb >> (r + 3)) & 1u);
      a0 |= rb[(size_t)(r + 0) << 5] & o0;
      a1 |= rb[(size_t)(r + 1) << 5] & o1;
      a2 |= rb[(size_t)(r + 2) << 5] & o2;
      a3 |= rb[(size_t)(r + 3) << 5] & o3;
    }
    u64 supp = (a0 | a1) | (a2 | a3);
    supp |= __shfl_xor(supp, 32);  // combine the two row-halves
    kw &= ~supp;                   // word c: kept rows never mutually suppress
  }

  int pc = (lane < 32) ? __popcll(kw) : 0;
  int pre = pc;
  for (int o = 1; o < 64; o <<= 1) {
    int v = __shfl_up(pre, o);
    if (lane >= o) pre += v;
  }
  int excl = pre - pc;
  int total = __shfl(pre, 63);

  float* ob = out;                              // [B,100,4]
  float* os = out + B_IMG * MAXOUT * 4;         // [B,100]
  float* ol = os + B_IMG * MAXOUT;              // [B,100]
  float* oi = ol + B_IMG * MAXOUT;              // [B,100]

  if (lane < 32) {
    u64 w = kw;
    int r = excl;
    while (w) {
      int bit = __ffsll((long long)w) - 1;
      w &= w - 1;
      if (r < MAXOUT) {
        int j = (lane << 6) + bit;
        size_t g = (size_t)b * K_NMS + j;
        float4 bx = raw4[g];
        int o = b * MAXOUT + r;
        ob[o * 4 + 0] = bx.x; ob[o * 4 + 1] = bx.y;
        ob[o * 4 + 2] = bx.z; ob[o * 4 + 3] = bx.w;
        os[o] = scoref[g];
        ol[o] = (float)labeli[g];
        oi[o] = (float)flati[g];
      }
      ++r;
    }
  }
  for (int r = total + lane; r < MAXOUT; r += 64) {
    int o = b * MAXOUT + r;
    ob[o * 4 + 0] = 0.f; ob[o * 4 + 1] = 0.f; ob[o * 4 + 2] = 0.f; ob[o * 4 + 3] = 0.f;
    os[o] = 0.f;
    ol[o] = -1.0f;
    oi[o] = -1.0f;
  }
}

// ---------------------------------------------------------------------------
extern "C" void kernel_launch(void* const* d_in, const int* in_sizes, int n_in,
                              void* d_out, int out_size, void* d_ws, size_t ws_size,
                              hipStream_t stream) {
  const float* cls = (const float*)d_in[0];
  const float* regs = (const float*)d_in[1];
  const float* props = (const float*)d_in[2];
  const int* pH = (const int*)d_in[3];
  const int* pW = (const int*)d_in[4];

  char* ws = (char*)d_ws;
  size_t o = 0;
  u32* hist = (u32*)(ws + o); o += (size_t)B_IMG * NBIN * sizeof(u32);    // 64 KB
  u32* gcnt = (u32*)(ws + o); o += (size_t)B_IMG * NSEG * sizeof(u32);    // 256 B
  size_t zero_bytes = o;  // hist + gcnt zeroed each call
  u32* cut = (u32*)(ws + o); o += 256;
  u64* glist = (u64*)(ws + o); o += (size_t)B_IMG * NSEG * GSEGCAP * sizeof(u64);
  u64* sorted = (u64*)(ws + o); o += (size_t)B_IMG * K_NMS * sizeof(u64);
  float4* raw4 = (float4*)(ws + o); o += (size_t)B_IMG * K_NMS * sizeof(float4);
  float4* off4 = (float4*)(ws + o); o += (size_t)B_IMG * K_NMS * sizeof(float4);
  float* area = (float*)(ws + o); o += (size_t)B_IMG * K_NMS * sizeof(float);
  float* scoref = (float*)(ws + o); o += (size_t)B_IMG * K_NMS * sizeof(float);
  int* labeli = (int*)(ws + o); o += (size_t)B_IMG * K_NMS * sizeof(int);
  int* flati = (int*)(ws + o); o += (size_t)B_IMG * K_NMS * sizeof(int);
  u64* masks = (u64*)(ws + o); o += (size_t)B_IMG * K_NMS * 32 * sizeof(u64);

  hipMemsetAsync(hist, 0, zero_bytes, stream);
  k_hist<<<B_IMG * N_ROI / 16, 1024, 0, stream>>>(cls, hist);
  k_cutoff<<<B_IMG, 1024, 0, stream>>>(hist, cut);
  k_gather<<<B_IMG * N_ROI / 16, 1024, 0, stream>>>(cls, cut, gcnt, glist);
  k_sort<<<B_IMG, 1024, 0, stream>>>(gcnt, glist, sorted);
  k_decode<<<B_IMG * K_NMS / 256, 256, 0, stream>>>(sorted, props, regs, pH, pW,
                                                    raw4, off4, area, scoref, labeli, flati);
  k_mask<<<B_IMG * K_NMS / 4, 256, 0, stream>>>(off4, area, masks);
  k_scanout<<<B_IMG, 64, 0, stream>>>(masks, scoref, raw4, labeli, flati, (float*)d_out);
}

// Round 6
// 128.262 us; speedup vs baseline: 8.7764x; 1.4819x over previous
//
#include <hip/hip_runtime.h>
#include <cstdint>
#include <cstddef>

#pragma clang fp contract(off)

typedef unsigned long long u64;
typedef unsigned int u32;

#define B_IMG 4
#define N_ROI 8192
#define NCLS 80
#define NCOL 81
#define K_NMS 2048
#define MAXOUT 100
#define THR_SCORE 0.05f
#define THR_IOU 0.5f

#define NBIN 4096
#define BIN_OFF 62771u  // (0x3D4CCCCD >> 14): bin of smallest float > 0.05f
#define NSEG 16
#define GSEGCAP 512
#define SORTN 4096

// ---------------------------------------------------------------------------
// Shared softmax: MUST be bit-identical between k_hist and k_gather (it is:
// same inline function, same reduction order, IEEE ops, contract off).
// ---------------------------------------------------------------------------
__device__ __forceinline__ void softmax_row(const float* __restrict__ row, int lane,
                                            float& s0, float& s1) {
  float v0 = row[lane];
  float v1 = (lane < NCOL - 64) ? row[64 + lane] : -1e38f;
  float m = fmaxf(v0, v1);
  for (int o = 32; o; o >>= 1) m = fmaxf(m, __shfl_xor(m, o));
  float e0 = expf(v0 - m);
  float e1 = (lane < NCOL - 64) ? expf(v1 - m) : 0.0f;
  float s = e0 + e1;
  for (int o = 32; o; o >>= 1) s += __shfl_xor(s, o);
  s0 = e0 / s;
  s1 = e1 / s;
}

// ---------------------------------------------------------------------------
// Kernel 1: per-image 4096-bin histogram of candidate score keys.
// ---------------------------------------------------------------------------
__global__ __launch_bounds__(1024) void k_hist(const float* __restrict__ cls,
                                               u32* __restrict__ hist) {
#pragma clang fp contract(off)
  __shared__ u32 lh[NBIN];
  int t = threadIdx.x;
  for (int i = t; i < NBIN; i += 1024) lh[i] = 0;
  __syncthreads();
  int wv = t >> 6, lane = t & 63;
  int wid = blockIdx.x * 16 + wv;  // 16 divides 8192 -> block within one image
  int b = wid >> 13;
  float s0, s1;
  softmax_row(cls + (size_t)wid * NCOL, lane, s0, s1);
  if (s0 > THR_SCORE) atomicAdd(&lh[(__float_as_uint(s0) >> 14) - BIN_OFF], 1u);
  if (lane < 16 && s1 > THR_SCORE) atomicAdd(&lh[(__float_as_uint(s1) >> 14) - BIN_OFF], 1u);
  __syncthreads();
  u32* gh = hist + (size_t)b * NBIN;
  for (int i = t; i < NBIN; i += 1024) {
    u32 c = lh[i];
    if (c) atomicAdd(&gh[i], c);
  }
}

// ---------------------------------------------------------------------------
// Kernel 2: per image, find largest bin c* with suffix_count(c*) >= 2048.
// ---------------------------------------------------------------------------
__global__ __launch_bounds__(1024) void k_cutoff(const u32* __restrict__ hist,
                                                 u32* __restrict__ cut) {
  __shared__ u32 wsum[16];
  __shared__ int best;
  int b = blockIdx.x, t = threadIdx.x;
  const u32* gh = hist + (size_t)b * NBIN;
  u32 v0 = gh[t * 4 + 0], v1 = gh[t * 4 + 1], v2 = gh[t * 4 + 2], v3 = gh[t * 4 + 3];
  u32 my = v0 + v1 + v2 + v3;
  int lane = t & 63, wv = t >> 6;
  u32 inc = my;
  for (int o = 1; o < 64; o <<= 1) {
    u32 x = __shfl_up(inc, o);
    if (lane >= o) inc += x;
  }
  if (lane == 63) wsum[wv] = inc;
  if (t == 0) best = 0;
  __syncthreads();
  u32 wpre = 0;
  for (int i = 0; i < wv; ++i) wpre += wsum[i];
  u32 total = 0;
  for (int i = 0; i < 16; ++i) total += wsum[i];
  u32 excl = wpre + (inc - my);  // prefix(bin t*4)
  if (total >= K_NMS) {
    u32 lim = total - K_NMS;
    u32 p = excl;
    int cand = -1;
    if (p <= lim) cand = t * 4 + 0; p += v0;
    if (p <= lim) cand = t * 4 + 1; p += v1;
    if (p <= lim) cand = t * 4 + 2; p += v2;
    if (p <= lim) cand = t * 4 + 3; p += v3;
    if (cand >= 0) atomicMax(&best, cand);
  }
  __syncthreads();
  if (t == 0) cut[b] = (total >= K_NMS) ? (u32)best : 0u;
}

// ---------------------------------------------------------------------------
// Kernel 3: recompute softmax, append items with bin >= cut[b] to 16 segments
// per image. Block-aggregated atomics.
// ---------------------------------------------------------------------------
__global__ __launch_bounds__(1024) void k_gather(const float* __restrict__ cls,
                                                 const u32* __restrict__ cut,
                                                 u32* __restrict__ gcnt,
                                                 u64* __restrict__ glist) {
#pragma clang fp contract(off)
  __shared__ u32 wbase[16];
  __shared__ u32 blkcnt;
  __shared__ u32 gbase;
  int t = threadIdx.x, wv = t >> 6, lane = t & 63;
  int wid = blockIdx.x * 16 + wv;
  int b = wid >> 13;
  int n = wid & (N_ROI - 1);
  if (t == 0) blkcnt = 0;
  __syncthreads();
  float s0, s1;
  softmax_row(cls + (size_t)wid * NCOL, lane, s0, s1);
  u32 c = cut[b];
  bool c0 = (s0 > THR_SCORE) && (((__float_as_uint(s0) >> 14) - BIN_OFF) >= c);
  bool c1 = (lane < 16) && (s1 > THR_SCORE) && (((__float_as_uint(s1) >> 14) - BIN_OFF) >= c);
  u64 b0 = __ballot(c0), b1 = __ballot(c1);
  int cnt = __popcll(b0) + __popcll(b1);
  if (lane == 0) wbase[wv] = atomicAdd(&blkcnt, (u32)cnt);
  __syncthreads();
  int seg = blockIdx.x & (NSEG - 1);  // 512 blocks/image -> 32 blocks/segment
  if (t == 0) gbase = atomicAdd(&gcnt[b * NSEG + seg], blkcnt);
  __syncthreads();
  u32 base = gbase + wbase[wv];
  u64 lm = (1ull << lane) - 1ull;
  u64* seglist = glist + ((size_t)(b * NSEG + seg)) * GSEGCAP;
  if (c0) {
    u32 pos = base + (u32)__popcll(b0 & lm);
    if (pos < GSEGCAP) {
      u32 flat = (u32)(n * NCLS + lane);
      seglist[pos] = ((u64)__float_as_uint(s0) << 32) | (u32)(~flat);
    }
  }
  if (c1) {
    u32 pos = base + (u32)__popcll(b0) + (u32)__popcll(b1 & lm);
    if (pos < GSEGCAP) {
      u32 flat = (u32)(n * NCLS + 64 + lane);
      seglist[pos] = ((u64)__float_as_uint(s1) << 32) | (u32)(~flat);
    }
  }
}

// ---------------------------------------------------------------------------
// Kernel 4: per-image bitonic sort (desc) of <=4096 gathered keys in LDS.
// ---------------------------------------------------------------------------
__device__ inline void cmpswap_desc(u64* s, int i, int p, bool desc) {
  u64 a = s[i], b = s[p];
  if ((a < b) == desc) { s[i] = b; s[p] = a; }
}

__global__ __launch_bounds__(1024) void k_sort(const u32* __restrict__ gcnt,
                                               const u64* __restrict__ glist,
                                               u64* __restrict__ sorted) {
  __shared__ u64 s[SORTN];
  __shared__ u32 pref[NSEG + 1];
  int b = blockIdx.x, t = threadIdx.x;
  if (t == 0) {
    u32 p = 0;
    for (int i = 0; i < NSEG; ++i) {
      pref[i] = p;
      u32 cc = gcnt[b * NSEG + i];
      if (cc > GSEGCAP) cc = GSEGCAP;
      p += cc;
    }
    pref[NSEG] = p;
  }
  __syncthreads();
  u32 T = pref[NSEG];
  if (T > SORTN) T = SORTN;
  for (int i = t; i < SORTN; i += 1024) {
    u64 v = 0;
    if ((u32)i < T) {
      int seg = 0;
      while (seg < NSEG - 1 && (u32)i >= pref[seg + 1]) ++seg;
      v = glist[((size_t)(b * NSEG + seg)) * GSEGCAP + ((u32)i - pref[seg])];
    }
    s[i] = v;
  }
  __syncthreads();
  for (int k = 2; k <= SORTN; k <<= 1) {
    for (int j = k >> 1; j > 0; j >>= 1) {
      for (int p = t; p < SORTN / 2; p += 1024) {
        int i = ((p & ~(j - 1)) << 1) | (p & (j - 1));
        cmpswap_desc(s, i, i | j, (i & k) == 0);
      }
      __syncthreads();
    }
  }
  for (int i = t; i < K_NMS; i += 1024) sorted[(size_t)b * K_NMS + i] = s[i];
}

// ---------------------------------------------------------------------------
// Kernel 5: decode the 2048 selected candidates (reference fp32 math exactly).
// ---------------------------------------------------------------------------
__global__ __launch_bounds__(256) void k_decode(const u64* __restrict__ sorted,
                                                const float* __restrict__ props,
                                                const float* __restrict__ regs,
                                                const int* __restrict__ pH,
                                                const int* __restrict__ pW,
                                                float4* __restrict__ raw4,
                                                float4* __restrict__ off4,
                                                float* __restrict__ area,
                                                float* __restrict__ scoref,
                                                int* __restrict__ labeli,
                                                int* __restrict__ flati) {
#pragma clang fp contract(off)
  int t = blockIdx.x * 256 + threadIdx.x;  // 0 .. B*K-1
  int b = t >> 11;
  u64 key = sorted[t];
  if (key == 0ull) {
    raw4[t] = make_float4(0.f, 0.f, 0.f, 0.f);
    off4[t] = make_float4(0.f, 0.f, 0.f, 0.f);
    area[t] = 0.f; scoref[t] = -1.0f; labeli[t] = 0; flati[t] = 0;
    return;
  }
  float Hf = (float)pH[0];
  float Wf = (float)pW[0];
  float offc = fmaxf(Hf, Wf) + 1.0f;  // 1334

  u32 flat = ~(u32)(key & 0xFFFFFFFFull);
  float sc = __uint_as_float((u32)(key >> 32));
  int n = (int)(flat / NCLS);
  int c = (int)(flat - (u32)n * NCLS);

  float4 p = ((const float4*)props)[b * N_ROI + n];
  const float4 dl = *(const float4*)(regs + ((size_t)(b * N_ROI + n)) * (NCLS * 4) + c * 4);

  float mr = fabsf(logf(16.0f / 1000.0f));
  float dx = dl.x * 0.1f;
  float dy = dl.y * 0.1f;
  float dw = fminf(fmaxf(dl.z * 0.2f, -mr), mr);
  float dh = fminf(fmaxf(dl.w * 0.2f, -mr), mr);

  float px = (p.x + p.z) * 0.5f;
  float py = (p.y + p.w) * 0.5f;
  float pw = p.z - p.x;
  float ph = p.w - p.y;

  float tx = pw * dx; float gx = px + tx;
  float ty = ph * dy; float gy = py + ty;
  float gw = pw * expf(dw);
  float gh = ph * expf(dh);
  float hx = gw * 0.5f, hy = gh * 0.5f;

  float x1 = fminf(fmaxf(gx - hx, 0.0f), Wf);
  float y1 = fminf(fmaxf(gy - hy, 0.0f), Hf);
  float x2 = fminf(fmaxf(gx + hx, 0.0f), Wf);
  float y2 = fminf(fmaxf(gy + hy, 0.0f), Hf);

  raw4[t] = make_float4(x1, y1, x2, y2);

  float off = (float)c * offc;
  float ox1 = x1 + off, oy1 = y1 + off, ox2 = x2 + off, oy2 = y2 + off;
  off4[t] = make_float4(ox1, oy1, ox2, oy2);
  area[t] = fmaxf(ox2 - ox1, 0.0f) * fmaxf(oy2 - oy1, 0.0f);
  scoref[t] = sc;
  labeli[t] = c;
  flati[t] = (int)flat;
}

// ---------------------------------------------------------------------------
// Kernel 6: suppression bitmask. Row i: bit j set iff (j>i) && IoU(i,j)>0.5.
// ---------------------------------------------------------------------------
__global__ __launch_bounds__(256) void k_mask(const float4* __restrict__ off4,
                                              const float* __restrict__ area,
                                              u64* __restrict__ masks) {
#pragma clang fp contract(off)
  int wave = threadIdx.x >> 6, lane = threadIdx.x & 63;
  int R = blockIdx.x * 4 + wave;  // 0 .. B*K-1
  int b = R >> 11, i = R & (K_NMS - 1);
  const float4* bb = off4 + (size_t)b * K_NMS;
  const float* aa = area + (size_t)b * K_NMS;
  float4 bi = bb[i];
  float ai = aa[i];
  u64 my = 0;
  for (int w = 0; w < 32; ++w) {
    int j = (w << 6) + lane;
    float4 bj = bb[j];
    float lx = fmaxf(bi.x, bj.x);
    float ly = fmaxf(bi.y, bj.y);
    float rx = fminf(bi.z, bj.z);
    float ry = fminf(bi.w, bj.w);
    float ww = fmaxf(rx - lx, 0.0f);
    float hh = fmaxf(ry - ly, 0.0f);
    float inter = ww * hh;
    float uni = (ai + aa[j]) - inter;
    float iou = inter / fmaxf(uni, 1e-6f);
    bool sup = (j > i) && (iou > THR_IOU);
    u64 word = __ballot(sup);
    if (lane == w) my = word;
  }
  if (lane < 32) masks[((size_t)R << 5) + lane] = my;
}

// ---------------------------------------------------------------------------
// Kernel 7: greedy scan, chunked closure form + EARLY TERMINATION.
// Output = first 100 kept rows; keep(i) depends only on rows < i. After
// chunk c, words 0..c are FINAL (mask has only j>i bits -> no later row can
// suppress an earlier one). Once >=100 rows are kept among finalized words,
// every later row has output rank >= 100 -> can never be emitted -> stop.
// Ranks computed afterwards for unfinalized words may be inflated, but are
// all >= 100 and get skipped by the (r < MAXOUT) guard; total >= 100 means
// the zero-fill loop doesn't run. Bit-exact same output as the full scan.
// ---------------------------------------------------------------------------
__global__ __launch_bounds__(64, 1) void k_scanout(const u64* __restrict__ masks,
                                                   const float* __restrict__ scoref,
                                                   const float4* __restrict__ raw4,
                                                   const int* __restrict__ labeli,
                                                   const int* __restrict__ flati,
                                                   float* __restrict__ out) {
  int b = blockIdx.x;
  int lane = threadIdx.x;

  // keep init: valid = score > 0; lane w (w<32) owns keep word w
  u64 kw = 0;
  for (int w = 0; w < 32; ++w) {
    bool pred = scoref[(size_t)b * K_NMS + (w << 6) + lane] > 0.0f;
    u64 word = __ballot(pred);
    if (lane == w) kw = word;
  }

  const u64* mrow = masks + ((size_t)b << 16);  // b * 2048 * 32
  int myw = lane & 31;
  int half = lane >> 5;

  // diag for chunk c: lane i -> mask[c*64 + i], word c. 1-chunk rotation.
  u64 dnext = mrow[((size_t)lane << 5) + 0];

  for (int c = 0; c < 32; ++c) {
    u64 dcur = dnext;
    if (c < 31) dnext = mrow[((size_t)((c + 1) * 64 + lane) << 5) + (c + 1)];

    // ---- (a) scalar closure of chunk c ----
    u32 dlo = (u32)dcur, dhi = (u32)(dcur >> 32);
    u64 kc = ((u64)(u32)__builtin_amdgcn_readlane((int)(u32)(kw >> 32), c) << 32) |
             (u32)__builtin_amdgcn_readlane((int)(u32)kw, c);
#pragma unroll
    for (int d = 0; d < 64; ++d) {
      u64 dg = ((u64)(u32)__builtin_amdgcn_readlane((int)dhi, d) << 32) |
               (u32)__builtin_amdgcn_readlane((int)dlo, d);
      u64 on = (u64)0 - ((kc >> d) & 1ull);
      kc &= ~(dg & on);
    }

    // ---- (b) apply suppression of kept rows to all 32 words ----
    u32 kb = half ? (u32)(kc >> 32) : (u32)kc;  // rows half*32..half*32+31
    const u64* rb = mrow + (((size_t)(c * 64 + half * 32)) << 5) + myw;
    u64 a0 = 0, a1 = 0, a2 = 0, a3 = 0;
#pragma unroll
    for (int r = 0; r < 32; r += 4) {
      u64 o0 = (u64)0 - (u64)((kb >> (r + 0)) & 1u);
      u64 o1 = (u64)0 - (u64)((kb >> (r + 1)) & 1u);
      u64 o2 = (u64)0 - (u64)((kb >> (r + 2)) & 1u);
      u64 o3 = (u64)0 - (u64)((kb >> (r + 3)) & 1u);
      a0 |= rb[(size_t)(r + 0) << 5] & o0;
      a1 |= rb[(size_t)(r + 1) << 5] & o1;
      a2 |= rb[(size_t)(r + 2) << 5] & o2;
      a3 |= rb[(size_t)(r + 3) << 5] & o3;
    }
    u64 supp = (a0 | a1) | (a2 | a3);
    supp |= __shfl_xor(supp, 32);  // combine the two row-halves
    kw &= ~supp;                   // word c: kept rows never mutually suppress

    // ---- early termination: count kept rows in FINALIZED words 0..c ----
    int fin = (lane <= c) ? __popcll(kw) : 0;  // lanes>=32 have kw==0
    for (int o = 32; o; o >>= 1) fin += __shfl_xor(fin, o);
    if (fin >= MAXOUT) break;
  }

  int pc = (lane < 32) ? __popcll(kw) : 0;
  int pre = pc;
  for (int o = 1; o < 64; o <<= 1) {
    int v = __shfl_up(pre, o);
    if (lane >= o) pre += v;
  }
  int excl = pre - pc;
  int total = __shfl(pre, 63);

  float* ob = out;                              // [B,100,4]
  float* os = out + B_IMG * MAXOUT * 4;         // [B,100]
  float* ol = os + B_IMG * MAXOUT;              // [B,100]
  float* oi = ol + B_IMG * MAXOUT;              // [B,100]

  if (lane < 32) {
    u64 w = kw;
    int r = excl;
    while (w) {
      int bit = __ffsll((long long)w) - 1;
      w &= w - 1;
      if (r < MAXOUT) {
        int j = (lane << 6) + bit;
        size_t g = (size_t)b * K_NMS + j;
        float4 bx = raw4[g];
        int o = b * MAXOUT + r;
        ob[o * 4 + 0] = bx.x; ob[o * 4 + 1] = bx.y;
        ob[o * 4 + 2] = bx.z; ob[o * 4 + 3] = bx.w;
        os[o] = scoref[g];
        ol[o] = (float)labeli[g];
        oi[o] = (float)flati[g];
      }
      ++r;
    }
  }
  for (int r = total + lane; r < MAXOUT; r += 64) {
    int o = b * MAXOUT + r;
    ob[o * 4 + 0] = 0.f; ob[o * 4 + 1] = 0.f; ob[o * 4 + 2] = 0.f; ob[o * 4 + 3] = 0.f;
    os[o] = 0.f;
    ol[o] = -1.0f;
    oi[o] = -1.0f;
  }
}

// ---------------------------------------------------------------------------
extern "C" void kernel_launch(void* const* d_in, const int* in_sizes, int n_in,
                              void* d_out, int out_size, void* d_ws, size_t ws_size,
                              hipStream_t stream) {
  const float* cls = (const float*)d_in[0];
  const float* regs = (const float*)d_in[1];
  const float* props = (const float*)d_in[2];
  const int* pH = (const int*)d_in[3];
  const int* pW = (const int*)d_in[4];

  char* ws = (char*)d_ws;
  size_t o = 0;
  u32* hist = (u32*)(ws + o); o += (size_t)B_IMG * NBIN * sizeof(u32);    // 64 KB
  u32* gcnt = (u32*)(ws + o); o += (size_t)B_IMG * NSEG * sizeof(u32);    // 256 B
  size_t zero_bytes = o;  // hist + gcnt zeroed each call
  u32* cut = (u32*)(ws + o); o += 256;
  u64* glist = (u64*)(ws + o); o += (size_t)B_IMG * NSEG * GSEGCAP * sizeof(u64);
  u64* sorted = (u64*)(ws + o); o += (size_t)B_IMG * K_NMS * sizeof(u64);
  float4* raw4 = (float4*)(ws + o); o += (size_t)B_IMG * K_NMS * sizeof(float4);
  float4* off4 = (float4*)(ws + o); o += (size_t)B_IMG * K_NMS * sizeof(float4);
  float* area = (float*)(ws + o); o += (size_t)B_IMG * K_NMS * sizeof(float);
  float* scoref = (float*)(ws + o); o += (size_t)B_IMG * K_NMS * sizeof(float);
  int* labeli = (int*)(ws + o); o += (size_t)B_IMG * K_NMS * sizeof(int);
  int* flati = (int*)(ws + o); o += (size_t)B_IMG * K_NMS * sizeof(int);
  u64* masks = (u64*)(ws + o); o += (size_t)B_IMG * K_NMS * 32 * sizeof(u64);

  hipMemsetAsync(hist, 0, zero_bytes, stream);
  k_hist<<<B_IMG * N_ROI / 16, 1024, 0, stream>>>(cls, hist);
  k_cutoff<<<B_IMG, 1024, 0, stream>>>(hist, cut);
  k_gather<<<B_IMG * N_ROI / 16, 1024, 0, stream>>>(cls, cut, gcnt, glist);
  k_sort<<<B_IMG, 1024, 0, stream>>>(gcnt, glist, sorted);
  k_decode<<<B_IMG * K_NMS / 256, 256, 0, stream>>>(sorted, props, regs, pH, pW,
                                                    raw4, off4, area, scoref, labeli, flati);
  k_mask<<<B_IMG * K_NMS / 4, 256, 0, stream>>>(off4, area, masks);
  k_scanout<<<B_IMG, 64, 0, stream>>>(masks, scoref, raw4, labeli, flati, (float*)d_out);
}

// Round 7
// 123.547 us; speedup vs baseline: 9.1113x; 1.0382x over previous
//
#include <hip/hip_runtime.h>
#include <cstdint>
#include <cstddef>

#pragma clang fp contract(off)

typedef unsigned long long u64;
typedef unsigned int u32;

#define B_IMG 4
#define N_ROI 8192
#define NCLS 80
#define NCOL 81
#define K_NMS 2048
#define MAXOUT 100
#define THR_SCORE 0.05f
#define THR_IOU 0.5f

#define NBIN 4096
#define BIN_OFF 62771u  // (0x3D4CCCCD >> 14): bin of smallest float > 0.05f
#define NSEG 16
#define GSEGCAP 4096
#define SORTN 4096

// ---------------------------------------------------------------------------
// Kernel 0: zero hist + gcnt (replaces hipMemsetAsync: the runtime fill path
// for this 65.8 KB region cost ~41 us/dispatch; this kernel is ~2 us).
// ---------------------------------------------------------------------------
__global__ __launch_bounds__(256) void k_zero(u32* __restrict__ p, int nwords) {
  int i = blockIdx.x * 256 + threadIdx.x;
  if (i < nwords) p[i] = 0;
}

// ---------------------------------------------------------------------------
// Softmax: bit-exact reference replication (IEEE, contract off, fixed order).
// ---------------------------------------------------------------------------
__device__ __forceinline__ void softmax_row(const float* __restrict__ row, int lane,
                                            float& s0, float& s1) {
  float v0 = row[lane];
  float v1 = (lane < NCOL - 64) ? row[64 + lane] : -1e38f;
  float m = fmaxf(v0, v1);
  for (int o = 32; o; o >>= 1) m = fmaxf(m, __shfl_xor(m, o));
  float e0 = expf(v0 - m);
  float e1 = (lane < NCOL - 64) ? expf(v1 - m) : 0.0f;
  float s = e0 + e1;
  for (int o = 32; o; o >>= 1) s += __shfl_xor(s, o);
  s0 = e0 / s;
  s1 = e1 / s;
}

// ---------------------------------------------------------------------------
// Kernel 1: softmax once per RoI; histogram candidate bins AND append keys
// (score_bits<<32 | ~flat) to 16 per-image segments. 16 RoIs per block.
// ---------------------------------------------------------------------------
__global__ __launch_bounds__(1024) void k_hist(const float* __restrict__ cls,
                                               u32* __restrict__ hist,
                                               u32* __restrict__ gcnt,
                                               u64* __restrict__ glist) {
#pragma clang fp contract(off)
  __shared__ u32 lh[NBIN];
  __shared__ u32 wbase[16];
  __shared__ u32 blkcnt;
  __shared__ u32 gbase;
  int t = threadIdx.x, wv = t >> 6, lane = t & 63;
  for (int i = t; i < NBIN; i += 1024) lh[i] = 0;
  if (t == 0) blkcnt = 0;
  __syncthreads();

  int wid = blockIdx.x * 16 + wv;  // 512 blocks per image
  int b = wid >> 13;
  int n = wid & (N_ROI - 1);

  float s0, s1;
  softmax_row(cls + (size_t)wid * NCOL, lane, s0, s1);
  bool c0 = s0 > THR_SCORE;
  bool c1 = (lane < 16) && (s1 > THR_SCORE);
  if (c0) atomicAdd(&lh[(__float_as_uint(s0) >> 14) - BIN_OFF], 1u);
  if (c1) atomicAdd(&lh[(__float_as_uint(s1) >> 14) - BIN_OFF], 1u);

  u64 b0 = __ballot(c0), b1 = __ballot(c1);
  int cnt = __popcll(b0) + __popcll(b1);
  if (lane == 0) wbase[wv] = atomicAdd(&blkcnt, (u32)cnt);
  __syncthreads();  // lh atomics + wbase complete

  int seg = blockIdx.x & (NSEG - 1);
  if (t == 0) gbase = atomicAdd(&gcnt[b * NSEG + seg], blkcnt);

  // merge LDS histogram while the gbase atomic is in flight
  u32* gh = hist + (size_t)b * NBIN;
  for (int i = t; i < NBIN; i += 1024) {
    u32 c = lh[i];
    if (c) atomicAdd(&gh[i], c);
  }
  __syncthreads();  // gbase visible

  u32 base = gbase + wbase[wv];
  u64 lm = (1ull << lane) - 1ull;
  u64* seglist = glist + ((size_t)(b * NSEG + seg)) * GSEGCAP;
  if (c0) {
    u32 pos = base + (u32)__popcll(b0 & lm);
    if (pos < GSEGCAP) {
      u32 flat = (u32)(n * NCLS + lane);
      seglist[pos] = ((u64)__float_as_uint(s0) << 32) | (u32)(~flat);
    }
  }
  if (c1) {
    u32 pos = base + (u32)__popcll(b0) + (u32)__popcll(b1 & lm);
    if (pos < GSEGCAP) {
      u32 flat = (u32)(n * NCLS + 64 + lane);
      seglist[pos] = ((u64)__float_as_uint(s1) << 32) | (u32)(~flat);
    }
  }
}

// ---------------------------------------------------------------------------
// Kernel 2 (fused): per image -- cutoff bin from hist, filter stored keys
// (bin >= cut), LDS-compact, bitonic sort desc 4096, decode top-2048.
// Full-key sort canonicalizes the nondeterministic compaction order.
// ---------------------------------------------------------------------------
__device__ inline void cmpswap_desc(u64* s, int i, int p, bool desc) {
  u64 a = s[i], b = s[p];
  if ((a < b) == desc) { s[i] = b; s[p] = a; }
}

__global__ __launch_bounds__(1024) void k_sortsel(const u32* __restrict__ hist,
                                                  const u32* __restrict__ gcnt,
                                                  const u64* __restrict__ glist,
                                                  const float* __restrict__ props,
                                                  const float* __restrict__ regs,
                                                  const int* __restrict__ pH,
                                                  const int* __restrict__ pW,
                                                  float4* __restrict__ raw4,
                                                  float4* __restrict__ off4,
                                                  float* __restrict__ area,
                                                  float* __restrict__ scoref,
                                                  int* __restrict__ labeli,
                                                  int* __restrict__ flati) {
#pragma clang fp contract(off)
  __shared__ u64 s[SORTN];
  __shared__ u32 wsum[16];
  __shared__ int best;
  __shared__ u32 cutsh, cntsh;
  int b = blockIdx.x, t = threadIdx.x;
  int lane = t & 63, wv = t >> 6;

  // ---- phase A: cutoff (largest bin with suffix count >= 2048) ----
  const u32* gh = hist + (size_t)b * NBIN;
  u32 v0 = gh[t * 4 + 0], v1 = gh[t * 4 + 1], v2 = gh[t * 4 + 2], v3 = gh[t * 4 + 3];
  u32 my = v0 + v1 + v2 + v3;
  u32 inc = my;
  for (int o = 1; o < 64; o <<= 1) {
    u32 x = __shfl_up(inc, o);
    if (lane >= o) inc += x;
  }
  if (lane == 63) wsum[wv] = inc;
  if (t == 0) { best = 0; cntsh = 0; }
  __syncthreads();
  u32 wpre = 0;
  for (int i = 0; i < wv; ++i) wpre += wsum[i];
  u32 total = 0;
  for (int i = 0; i < 16; ++i) total += wsum[i];
  u32 excl = wpre + (inc - my);
  if (total >= K_NMS) {
    u32 lim = total - K_NMS;
    u32 p = excl;
    int cand = -1;
    if (p <= lim) cand = t * 4 + 0; p += v0;
    if (p <= lim) cand = t * 4 + 1; p += v1;
    if (p <= lim) cand = t * 4 + 2; p += v2;
    if (p <= lim) cand = t * 4 + 3; p += v3;
    if (cand >= 0) atomicMax(&best, cand);
  }
  __syncthreads();
  if (t == 0) cutsh = (total >= K_NMS) ? (u32)best : 0u;
  __syncthreads();

  // ---- phase B: filter stored keys, compact into LDS ----
  u32 cut = cutsh;
  for (int seg = 0; seg < NSEG; ++seg) {
    u32 m = gcnt[b * NSEG + seg];
    if (m > GSEGCAP) m = GSEGCAP;
    const u64* sl = glist + ((size_t)(b * NSEG + seg)) * GSEGCAP;
    for (u32 i = t; i < m; i += 1024) {
      u64 key = sl[i];
      u32 bin = (u32)(key >> 46) - BIN_OFF;
      if (bin >= cut) {
        u32 p = atomicAdd(&cntsh, 1u);
        if (p < SORTN) s[p] = key;
      }
    }
  }
  __syncthreads();
  u32 T = cntsh;
  if (T > SORTN) T = SORTN;
  for (int i = t; i < SORTN; i += 1024)
    if ((u32)i >= T) s[i] = 0ull;
  __syncthreads();

  // ---- phase C: bitonic sort desc ----
  for (int k = 2; k <= SORTN; k <<= 1) {
    for (int j = k >> 1; j > 0; j >>= 1) {
      for (int p = t; p < SORTN / 2; p += 1024) {
        int i = ((p & ~(j - 1)) << 1) | (p & (j - 1));
        cmpswap_desc(s, i, i | j, (i & k) == 0);
      }
      __syncthreads();
    }
  }

  // ---- phase D: decode top-2048 (reference fp32 math exactly) ----
  float Hf = (float)pH[0];
  float Wf = (float)pW[0];
  float offc = fmaxf(Hf, Wf) + 1.0f;  // 1334
  float mr = fabsf(logf(16.0f / 1000.0f));

  for (int q = t; q < K_NMS; q += 1024) {
    size_t g = (size_t)b * K_NMS + q;
    u64 key = s[q];
    if (key == 0ull) {
      raw4[g] = make_float4(0.f, 0.f, 0.f, 0.f);
      off4[g] = make_float4(0.f, 0.f, 0.f, 0.f);
      area[g] = 0.f; scoref[g] = -1.0f; labeli[g] = 0; flati[g] = 0;
      continue;
    }
    u32 flat = ~(u32)(key & 0xFFFFFFFFull);
    float sc = __uint_as_float((u32)(key >> 32));
    int n = (int)(flat / NCLS);
    int c = (int)(flat - (u32)n * NCLS);

    float4 p = ((const float4*)props)[b * N_ROI + n];
    const float4 dl = *(const float4*)(regs + ((size_t)(b * N_ROI + n)) * (NCLS * 4) + c * 4);

    float dx = dl.x * 0.1f;
    float dy = dl.y * 0.1f;
    float dw = fminf(fmaxf(dl.z * 0.2f, -mr), mr);
    float dh = fminf(fmaxf(dl.w * 0.2f, -mr), mr);

    float px = (p.x + p.z) * 0.5f;
    float py = (p.y + p.w) * 0.5f;
    float pw = p.z - p.x;
    float ph = p.w - p.y;

    float tx = pw * dx; float gx = px + tx;
    float ty = ph * dy; float gy = py + ty;
    float gw = pw * expf(dw);
    float gh2 = ph * expf(dh);
    float hx = gw * 0.5f, hy = gh2 * 0.5f;

    float x1 = fminf(fmaxf(gx - hx, 0.0f), Wf);
    float y1 = fminf(fmaxf(gy - hy, 0.0f), Hf);
    float x2 = fminf(fmaxf(gx + hx, 0.0f), Wf);
    float y2 = fminf(fmaxf(gy + hy, 0.0f), Hf);

    raw4[g] = make_float4(x1, y1, x2, y2);

    float off = (float)c * offc;
    float ox1 = x1 + off, oy1 = y1 + off, ox2 = x2 + off, oy2 = y2 + off;
    off4[g] = make_float4(ox1, oy1, ox2, oy2);
    area[g] = fmaxf(ox2 - ox1, 0.0f) * fmaxf(oy2 - oy1, 0.0f);
    scoref[g] = sc;
    labeli[g] = c;
    flati[g] = (int)flat;
  }
}

// ---------------------------------------------------------------------------
// Kernel 3: suppression bitmask, triangular. Words fully below the diagonal
// are all-zero by construction (sup requires j>i) -> write 0 without IoU.
// ---------------------------------------------------------------------------
__global__ __launch_bounds__(256) void k_mask(const float4* __restrict__ off4,
                                              const float* __restrict__ area,
                                              u64* __restrict__ masks) {
#pragma clang fp contract(off)
  int wave = threadIdx.x >> 6, lane = threadIdx.x & 63;
  int R = blockIdx.x * 4 + wave;  // 0 .. B*K-1
  int b = R >> 11, i = R & (K_NMS - 1);
  const float4* bb = off4 + (size_t)b * K_NMS;
  const float* aa = area + (size_t)b * K_NMS;
  float4 bi = bb[i];
  float ai = aa[i];
  u64 my = 0;
  for (int w = i >> 6; w < 32; ++w) {  // words < i/64 are all-zero
    int j = (w << 6) + lane;
    float4 bj = bb[j];
    float lx = fmaxf(bi.x, bj.x);
    float ly = fmaxf(bi.y, bj.y);
    float rx = fminf(bi.z, bj.z);
    float ry = fminf(bi.w, bj.w);
    float ww = fmaxf(rx - lx, 0.0f);
    float hh = fmaxf(ry - ly, 0.0f);
    float inter = ww * hh;
    float uni = (ai + aa[j]) - inter;
    float iou = inter / fmaxf(uni, 1e-6f);
    bool sup = (j > i) && (iou > THR_IOU);
    u64 word = __ballot(sup);
    if (lane == w) my = word;
  }
  if (lane < 32) masks[((size_t)R << 5) + lane] = my;
}

// ---------------------------------------------------------------------------
// Kernel 4: greedy scan, chunked closure + early termination (see R5/R6).
// ---------------------------------------------------------------------------
__global__ __launch_bounds__(64, 1) void k_scanout(const u64* __restrict__ masks,
                                                   const float* __restrict__ scoref,
                                                   const float4* __restrict__ raw4,
                                                   const int* __restrict__ labeli,
                                                   const int* __restrict__ flati,
                                                   float* __restrict__ out) {
  int b = blockIdx.x;
  int lane = threadIdx.x;

  u64 kw = 0;
  for (int w = 0; w < 32; ++w) {
    bool pred = scoref[(size_t)b * K_NMS + (w << 6) + lane] > 0.0f;
    u64 word = __ballot(pred);
    if (lane == w) kw = word;
  }

  const u64* mrow = masks + ((size_t)b << 16);  // b * 2048 * 32
  int myw = lane & 31;
  int half = lane >> 5;

  u64 dnext = mrow[((size_t)lane << 5) + 0];

  for (int c = 0; c < 32; ++c) {
    u64 dcur = dnext;
    if (c < 31) dnext = mrow[((size_t)((c + 1) * 64 + lane) << 5) + (c + 1)];

    // (a) scalar closure of chunk c
    u32 dlo = (u32)dcur, dhi = (u32)(dcur >> 32);
    u64 kc = ((u64)(u32)__builtin_amdgcn_readlane((int)(u32)(kw >> 32), c) << 32) |
             (u32)__builtin_amdgcn_readlane((int)(u32)kw, c);
#pragma unroll
    for (int d = 0; d < 64; ++d) {
      u64 dg = ((u64)(u32)__builtin_amdgcn_readlane((int)dhi, d) << 32) |
               (u32)__builtin_amdgcn_readlane((int)dlo, d);
      u64 on = (u64)0 - ((kc >> d) & 1ull);
      kc &= ~(dg & on);
    }

    // (b) apply suppression of kept rows to all 32 words
    u32 kb = half ? (u32)(kc >> 32) : (u32)kc;
    const u64* rb = mrow + (((size_t)(c * 64 + half * 32)) << 5) + myw;
    u64 a0 = 0, a1 = 0, a2 = 0, a3 = 0;
#pragma unroll
    for (int r = 0; r < 32; r += 4) {
      u64 o0 = (u64)0 - (u64)((kb >> (r + 0)) & 1u);
      u64 o1 = (u64)0 - (u64)((kb >> (r + 1)) & 1u);
      u64 o2 = (u64)0 - (u64)((kb >> (r + 2)) & 1u);
      u64 o3 = (u64)0 - (u64)((kb >> (r + 3)) & 1u);
      a0 |= rb[(size_t)(r + 0) << 5] & o0;
      a1 |= rb[(size_t)(r + 1) << 5] & o1;
      a2 |= rb[(size_t)(r + 2) << 5] & o2;
      a3 |= rb[(size_t)(r + 3) << 5] & o3;
    }
    u64 supp = (a0 | a1) | (a2 | a3);
    supp |= __shfl_xor(supp, 32);
    kw &= ~supp;

    // early termination: kept rows in FINALIZED words 0..c
    int fin = (lane <= c) ? __popcll(kw) : 0;
    for (int o = 32; o; o >>= 1) fin += __shfl_xor(fin, o);
    if (fin >= MAXOUT) break;
  }

  int pc = (lane < 32) ? __popcll(kw) : 0;
  int pre = pc;
  for (int o = 1; o < 64; o <<= 1) {
    int v = __shfl_up(pre, o);
    if (lane >= o) pre += v;
  }
  int excl = pre - pc;
  int total = __shfl(pre, 63);

  float* ob = out;                              // [B,100,4]
  float* os = out + B_IMG * MAXOUT * 4;         // [B,100]
  float* ol = os + B_IMG * MAXOUT;              // [B,100]
  float* oi = ol + B_IMG * MAXOUT;              // [B,100]

  if (lane < 32) {
    u64 w = kw;
    int r = excl;
    while (w) {
      int bit = __ffsll((long long)w) - 1;
      w &= w - 1;
      if (r < MAXOUT) {
        int j = (lane << 6) + bit;
        size_t g = (size_t)b * K_NMS + j;
        float4 bx = raw4[g];
        int o = b * MAXOUT + r;
        ob[o * 4 + 0] = bx.x; ob[o * 4 + 1] = bx.y;
        ob[o * 4 + 2] = bx.z; ob[o * 4 + 3] = bx.w;
        os[o] = scoref[g];
        ol[o] = (float)labeli[g];
        oi[o] = (float)flati[g];
      }
      ++r;
    }
  }
  for (int r = total + lane; r < MAXOUT; r += 64) {
    int o = b * MAXOUT + r;
    ob[o * 4 + 0] = 0.f; ob[o * 4 + 1] = 0.f; ob[o * 4 + 2] = 0.f; ob[o * 4 + 3] = 0.f;
    os[o] = 0.f;
    ol[o] = -1.0f;
    oi[o] = -1.0f;
  }
}

// ---------------------------------------------------------------------------
extern "C" void kernel_launch(void* const* d_in, const int* in_sizes, int n_in,
                              void* d_out, int out_size, void* d_ws, size_t ws_size,
                              hipStream_t stream) {
  const float* cls = (const float*)d_in[0];
  const float* regs = (const float*)d_in[1];
  const float* props = (const float*)d_in[2];
  const int* pH = (const int*)d_in[3];
  const int* pW = (const int*)d_in[4];

  char* ws = (char*)d_ws;
  size_t o = 0;
  u32* hist = (u32*)(ws + o); o += (size_t)B_IMG * NBIN * sizeof(u32);    // 64 KB
  u32* gcnt = (u32*)(ws + o); o += (size_t)B_IMG * NSEG * sizeof(u32);    // 256 B
  int zero_words = (int)((size_t)B_IMG * NBIN + (size_t)B_IMG * NSEG);    // 16448
  u64* glist = (u64*)(ws + o); o += (size_t)B_IMG * NSEG * GSEGCAP * sizeof(u64);  // 2 MB
  float4* raw4 = (float4*)(ws + o); o += (size_t)B_IMG * K_NMS * sizeof(float4);
  float4* off4 = (float4*)(ws + o); o += (size_t)B_IMG * K_NMS * sizeof(float4);
  float* area = (float*)(ws + o); o += (size_t)B_IMG * K_NMS * sizeof(float);
  float* scoref = (float*)(ws + o); o += (size_t)B_IMG * K_NMS * sizeof(float);
  int* labeli = (int*)(ws + o); o += (size_t)B_IMG * K_NMS * sizeof(int);
  int* flati = (int*)(ws + o); o += (size_t)B_IMG * K_NMS * sizeof(int);
  u64* masks = (u64*)(ws + o); o += (size_t)B_IMG * K_NMS * 32 * sizeof(u64);

  k_zero<<<(zero_words + 255) / 256, 256, 0, stream>>>(hist, zero_words);
  k_hist<<<B_IMG * N_ROI / 16, 1024, 0, stream>>>(cls, hist, gcnt, glist);
  k_sortsel<<<B_IMG, 1024, 0, stream>>>(hist, gcnt, glist, props, regs, pH, pW,
                                        raw4, off4, area, scoref, labeli, flati);
  k_mask<<<B_IMG * K_NMS / 4, 256, 0, stream>>>(off4, area, masks);
  k_scanout<<<B_IMG, 64, 0, stream>>>(masks, scoref, raw4, labeli, flati, (float*)d_out);
}

// Round 8
// 86.586 us; speedup vs baseline: 13.0008x; 1.4269x over previous
//
#include <hip/hip_runtime.h>
#include <cstdint>
#include <cstddef>

#pragma clang fp contract(off)

typedef unsigned long long u64;
typedef unsigned int u32;

#define B_IMG 4
#define N_ROI 8192
#define NCLS 80
#define NCOL 81
#define K_NMS 2048
#define MAXOUT 100
#define THR_SCORE 0.05f
#define THR_IOU 0.5f

#define NBIN 4096
#define BIN_OFF 62771u  // (0x3D4CCCCD >> 14): bin of smallest float > 0.05f
#define NSEG 16
#define GSEGCAP 4096
#define STGN 4096  // staging capacity per image (>= 2048 + max bin size)

// ---------------------------------------------------------------------------
// Kernel 0: zero hist + gcnt + bincnt + sorted (contiguous region).
// ---------------------------------------------------------------------------
__global__ __launch_bounds__(256) void k_zero(u32* __restrict__ p, int nwords) {
  int i = blockIdx.x * 256 + threadIdx.x;
  if (i < nwords) p[i] = 0;
}

// ---------------------------------------------------------------------------
// Softmax: bit-exact reference replication (IEEE, contract off, fixed order).
// ---------------------------------------------------------------------------
__device__ __forceinline__ void softmax_row(const float* __restrict__ row, int lane,
                                            float& s0, float& s1) {
  float v0 = row[lane];
  float v1 = (lane < NCOL - 64) ? row[64 + lane] : -1e38f;
  float m = fmaxf(v0, v1);
  for (int o = 32; o; o >>= 1) m = fmaxf(m, __shfl_xor(m, o));
  float e0 = expf(v0 - m);
  float e1 = (lane < NCOL - 64) ? expf(v1 - m) : 0.0f;
  float s = e0 + e1;
  for (int o = 32; o; o >>= 1) s += __shfl_xor(s, o);
  s0 = e0 / s;
  s1 = e1 / s;
}

// ---------------------------------------------------------------------------
// Kernel 1: softmax once per RoI; histogram candidate bins AND append keys
// (score_bits<<32 | ~flat) to 16 per-image segments. 16 RoIs per block.
// ---------------------------------------------------------------------------
__global__ __launch_bounds__(1024) void k_hist(const float* __restrict__ cls,
                                               u32* __restrict__ hist,
                                               u32* __restrict__ gcnt,
                                               u64* __restrict__ glist) {
#pragma clang fp contract(off)
  __shared__ u32 lh[NBIN];
  __shared__ u32 wbase[16];
  __shared__ u32 blkcnt;
  __shared__ u32 gbase;
  int t = threadIdx.x, wv = t >> 6, lane = t & 63;
  for (int i = t; i < NBIN; i += 1024) lh[i] = 0;
  if (t == 0) blkcnt = 0;
  __syncthreads();

  int wid = blockIdx.x * 16 + wv;  // 512 blocks per image
  int b = wid >> 13;
  int n = wid & (N_ROI - 1);

  float s0, s1;
  softmax_row(cls + (size_t)wid * NCOL, lane, s0, s1);
  bool c0 = s0 > THR_SCORE;
  bool c1 = (lane < 16) && (s1 > THR_SCORE);
  if (c0) atomicAdd(&lh[(__float_as_uint(s0) >> 14) - BIN_OFF], 1u);
  if (c1) atomicAdd(&lh[(__float_as_uint(s1) >> 14) - BIN_OFF], 1u);

  u64 b0 = __ballot(c0), b1 = __ballot(c1);
  int cnt = __popcll(b0) + __popcll(b1);
  if (lane == 0) wbase[wv] = atomicAdd(&blkcnt, (u32)cnt);
  __syncthreads();  // lh atomics + wbase complete

  int seg = blockIdx.x & (NSEG - 1);
  if (t == 0) gbase = atomicAdd(&gcnt[b * NSEG + seg], blkcnt);

  // merge LDS histogram while the gbase atomic is in flight
  u32* gh = hist + (size_t)b * NBIN;
  for (int i = t; i < NBIN; i += 1024) {
    u32 c = lh[i];
    if (c) atomicAdd(&gh[i], c);
  }
  __syncthreads();  // gbase visible

  u32 base = gbase + wbase[wv];
  u64 lm = (1ull << lane) - 1ull;
  u64* seglist = glist + ((size_t)(b * NSEG + seg)) * GSEGCAP;
  if (c0) {
    u32 pos = base + (u32)__popcll(b0 & lm);
    if (pos < GSEGCAP) {
      u32 flat = (u32)(n * NCLS + lane);
      seglist[pos] = ((u64)__float_as_uint(s0) << 32) | (u32)(~flat);
    }
  }
  if (c1) {
    u32 pos = base + (u32)__popcll(b0) + (u32)__popcll(b1 & lm);
    if (pos < GSEGCAP) {
      u32 flat = (u32)(n * NCLS + 64 + lane);
      seglist[pos] = ((u64)__float_as_uint(s1) << 32) | (u32)(~flat);
    }
  }
}

// ---------------------------------------------------------------------------
// Kernel 2: per image -- cutoff bin, per-bin sorted-order base offsets
// (base[bin] = # keys in bins > bin), kept count. One block per image.
// ---------------------------------------------------------------------------
__global__ __launch_bounds__(1024) void k_cutbase(const u32* __restrict__ hist,
                                                  u32* __restrict__ cutg,
                                                  u32* __restrict__ binbase,
                                                  u32* __restrict__ keptT) {
  __shared__ u32 wsum[16];
  __shared__ int best;
  __shared__ u32 cutsh;
  int b = blockIdx.x, t = threadIdx.x;
  int lane = t & 63, wv = t >> 6;
  const u32* gh = hist + (size_t)b * NBIN;
  u32 v0 = gh[t * 4 + 0], v1 = gh[t * 4 + 1], v2 = gh[t * 4 + 2], v3 = gh[t * 4 + 3];
  u32 my = v0 + v1 + v2 + v3;
  u32 inc = my;
  for (int o = 1; o < 64; o <<= 1) {
    u32 x = __shfl_up(inc, o);
    if (lane >= o) inc += x;
  }
  if (lane == 63) wsum[wv] = inc;
  if (t == 0) best = 0;
  __syncthreads();
  u32 wpre = 0;
  for (int i = 0; i < wv; ++i) wpre += wsum[i];
  u32 total = 0;
  for (int i = 0; i < 16; ++i) total += wsum[i];
  u32 excl = wpre + (inc - my);  // prefix_excl(bin t*4)

  // base[bin] = total - prefix_incl(bin) = count of keys in strictly higher bins
  u32* bb = binbase + (size_t)b * NBIN + t * 4;
  u32 pi = excl;
  pi += v0; bb[0] = total - pi;
  pi += v1; bb[1] = total - pi;
  pi += v2; bb[2] = total - pi;
  pi += v3; bb[3] = total - pi;

  if (total >= K_NMS) {
    u32 lim = total - K_NMS;
    u32 p = excl;
    int cand = -1;
    if (p <= lim) cand = t * 4 + 0; p += v0;
    if (p <= lim) cand = t * 4 + 1; p += v1;
    if (p <= lim) cand = t * 4 + 2; p += v2;
    if (p <= lim) cand = t * 4 + 3; p += v3;
    if (cand >= 0) atomicMax(&best, cand);
  }
  __syncthreads();
  if (t == 0) {
    u32 c = (total >= K_NMS) ? (u32)best : 0u;
    cutsh = c;
    cutg[b] = c;
  }
  __syncthreads();
  u32 c = cutsh;
  if (t == (int)(c >> 2)) {
    u32 pe = excl;
    int r = (int)(c & 3);
    if (r > 0) pe += v0;
    if (r > 1) pe += v1;
    if (r > 2) pe += v2;
    keptT[b] = total - pe;  // count of keys with bin >= cut
  }
}

// ---------------------------------------------------------------------------
// Kernel 3: scatter kept keys into their bin's slot range in staging.
// Atomics spread over ~2500 bins -> negligible contention.
// ---------------------------------------------------------------------------
__global__ __launch_bounds__(256) void k_scatter(const u32* __restrict__ gcnt,
                                                 const u64* __restrict__ glist,
                                                 const u32* __restrict__ cutg,
                                                 const u32* __restrict__ binbase,
                                                 u32* __restrict__ bincnt,
                                                 u64* __restrict__ staging) {
  int sid = blockIdx.x;  // 0 .. B*NSEG-1
  int b = sid >> 4;
  u32 c = cutg[b];
  u32 m = gcnt[sid];
  if (m > GSEGCAP) m = GSEGCAP;
  const u64* sl = glist + (size_t)sid * GSEGCAP;
  for (u32 i = threadIdx.x; i < m; i += 256) {
    u64 key = sl[i];
    u32 bin = (u32)(key >> 46) - BIN_OFF;
    if (bin >= c) {
      u32 slot = binbase[(size_t)b * NBIN + bin] +
                 atomicAdd(&bincnt[(size_t)b * NBIN + bin], 1u);
      if (slot < STGN) staging[(size_t)b * STGN + slot] = key;
    }
  }
}

// ---------------------------------------------------------------------------
// Kernel 4: exact rank within bin (scan own bin's segment, avg ~7 keys),
// write sorted[rank] directly. Keys distinct -> deterministic, identical to
// a full descending sort of the kept set.
// ---------------------------------------------------------------------------
__global__ __launch_bounds__(256) void k_rankwrite(const u32* __restrict__ keptT,
                                                   const u32* __restrict__ binbase,
                                                   const u32* __restrict__ bincnt,
                                                   const u64* __restrict__ staging,
                                                   u64* __restrict__ sorted) {
  int p = blockIdx.x * 256 + threadIdx.x;  // 0 .. B*STGN-1
  int b = p >> 12;
  int i = p & (STGN - 1);
  u32 T = keptT[b];
  if (T > STGN) T = STGN;
  if ((u32)i >= T) return;
  u64 key = staging[(size_t)b * STGN + i];
  u32 bin = (u32)(key >> 46) - BIN_OFF;
  u32 base = binbase[(size_t)b * NBIN + bin];
  u32 cnt = bincnt[(size_t)b * NBIN + bin];
  u32 end = base + cnt;
  if (end > STGN) end = STGN;
  u32 rank = 0;
  for (u32 j = base; j < end; ++j)
    rank += (staging[(size_t)b * STGN + j] > key) ? 1u : 0u;
  u32 g = base + rank;
  if (g < K_NMS) sorted[(size_t)b * K_NMS + g] = key;
}

// ---------------------------------------------------------------------------
// Kernel 5: decode the 2048 selected candidates (reference fp32 math exactly).
// ---------------------------------------------------------------------------
__global__ __launch_bounds__(256) void k_decode(const u64* __restrict__ sorted,
                                                const float* __restrict__ props,
                                                const float* __restrict__ regs,
                                                const int* __restrict__ pH,
                                                const int* __restrict__ pW,
                                                float4* __restrict__ raw4,
                                                float4* __restrict__ off4,
                                                float* __restrict__ area,
                                                float* __restrict__ scoref,
                                                int* __restrict__ labeli,
                                                int* __restrict__ flati) {
#pragma clang fp contract(off)
  int t = blockIdx.x * 256 + threadIdx.x;  // 0 .. B*K-1
  int b = t >> 11;
  u64 key = sorted[t];
  if (key == 0ull) {
    raw4[t] = make_float4(0.f, 0.f, 0.f, 0.f);
    off4[t] = make_float4(0.f, 0.f, 0.f, 0.f);
    area[t] = 0.f; scoref[t] = -1.0f; labeli[t] = 0; flati[t] = 0;
    return;
  }
  float Hf = (float)pH[0];
  float Wf = (float)pW[0];
  float offc = fmaxf(Hf, Wf) + 1.0f;  // 1334

  u32 flat = ~(u32)(key & 0xFFFFFFFFull);
  float sc = __uint_as_float((u32)(key >> 32));
  int n = (int)(flat / NCLS);
  int c = (int)(flat - (u32)n * NCLS);

  float4 p = ((const float4*)props)[b * N_ROI + n];
  const float4 dl = *(const float4*)(regs + ((size_t)(b * N_ROI + n)) * (NCLS * 4) + c * 4);

  float mr = fabsf(logf(16.0f / 1000.0f));
  float dx = dl.x * 0.1f;
  float dy = dl.y * 0.1f;
  float dw = fminf(fmaxf(dl.z * 0.2f, -mr), mr);
  float dh = fminf(fmaxf(dl.w * 0.2f, -mr), mr);

  float px = (p.x + p.z) * 0.5f;
  float py = (p.y + p.w) * 0.5f;
  float pw = p.z - p.x;
  float ph = p.w - p.y;

  float tx = pw * dx; float gx = px + tx;
  float ty = ph * dy; float gy = py + ty;
  float gw = pw * expf(dw);
  float gh = ph * expf(dh);
  float hx = gw * 0.5f, hy = gh * 0.5f;

  float x1 = fminf(fmaxf(gx - hx, 0.0f), Wf);
  float y1 = fminf(fmaxf(gy - hy, 0.0f), Hf);
  float x2 = fminf(fmaxf(gx + hx, 0.0f), Wf);
  float y2 = fminf(fmaxf(gy + hy, 0.0f), Hf);

  raw4[t] = make_float4(x1, y1, x2, y2);

  float off = (float)c * offc;
  float ox1 = x1 + off, oy1 = y1 + off, ox2 = x2 + off, oy2 = y2 + off;
  off4[t] = make_float4(ox1, oy1, ox2, oy2);
  area[t] = fmaxf(ox2 - ox1, 0.0f) * fmaxf(oy2 - oy1, 0.0f);
  scoref[t] = sc;
  labeli[t] = c;
  flati[t] = (int)flat;
}

// ---------------------------------------------------------------------------
// Kernel 6: suppression bitmask, triangular (words below diagonal written 0).
// ---------------------------------------------------------------------------
__global__ __launch_bounds__(256) void k_mask(const float4* __restrict__ off4,
                                              const float* __restrict__ area,
                                              u64* __restrict__ masks) {
#pragma clang fp contract(off)
  int wave = threadIdx.x >> 6, lane = threadIdx.x & 63;
  int R = blockIdx.x * 4 + wave;  // 0 .. B*K-1
  int b = R >> 11, i = R & (K_NMS - 1);
  const float4* bb = off4 + (size_t)b * K_NMS;
  const float* aa = area + (size_t)b * K_NMS;
  float4 bi = bb[i];
  float ai = aa[i];
  u64 my = 0;
  for (int w = i >> 6; w < 32; ++w) {
    int j = (w << 6) + lane;
    float4 bj = bb[j];
    float lx = fmaxf(bi.x, bj.x);
    float ly = fmaxf(bi.y, bj.y);
    float rx = fminf(bi.z, bj.z);
    float ry = fminf(bi.w, bj.w);
    float ww = fmaxf(rx - lx, 0.0f);
    float hh = fmaxf(ry - ly, 0.0f);
    float inter = ww * hh;
    float uni = (ai + aa[j]) - inter;
    float iou = inter / fmaxf(uni, 1e-6f);
    bool sup = (j > i) && (iou > THR_IOU);
    u64 word = __ballot(sup);
    if (lane == w) my = word;
  }
  if (lane < 32) masks[((size_t)R << 5) + lane] = my;
}

// ---------------------------------------------------------------------------
// Kernel 7: greedy scan, chunked closure + early termination.
// ---------------------------------------------------------------------------
__global__ __launch_bounds__(64, 1) void k_scanout(const u64* __restrict__ masks,
                                                   const float* __restrict__ scoref,
                                                   const float4* __restrict__ raw4,
                                                   const int* __restrict__ labeli,
                                                   const int* __restrict__ flati,
                                                   float* __restrict__ out) {
  int b = blockIdx.x;
  int lane = threadIdx.x;

  u64 kw = 0;
  for (int w = 0; w < 32; ++w) {
    bool pred = scoref[(size_t)b * K_NMS + (w << 6) + lane] > 0.0f;
    u64 word = __ballot(pred);
    if (lane == w) kw = word;
  }

  const u64* mrow = masks + ((size_t)b << 16);  // b * 2048 * 32
  int myw = lane & 31;
  int half = lane >> 5;

  u64 dnext = mrow[((size_t)lane << 5) + 0];

  for (int c = 0; c < 32; ++c) {
    u64 dcur = dnext;
    if (c < 31) dnext = mrow[((size_t)((c + 1) * 64 + lane) << 5) + (c + 1)];

    // (a) scalar closure of chunk c
    u32 dlo = (u32)dcur, dhi = (u32)(dcur >> 32);
    u64 kc = ((u64)(u32)__builtin_amdgcn_readlane((int)(u32)(kw >> 32), c) << 32) |
             (u32)__builtin_amdgcn_readlane((int)(u32)kw, c);
#pragma unroll
    for (int d = 0; d < 64; ++d) {
      u64 dg = ((u64)(u32)__builtin_amdgcn_readlane((int)dhi, d) << 32) |
               (u32)__builtin_amdgcn_readlane((int)dlo, d);
      u64 on = (u64)0 - ((kc >> d) & 1ull);
      kc &= ~(dg & on);
    }

    // (b) apply suppression of kept rows to all 32 words
    u32 kb = half ? (u32)(kc >> 32) : (u32)kc;
    const u64* rb = mrow + (((size_t)(c * 64 + half * 32)) << 5) + myw;
    u64 a0 = 0, a1 = 0, a2 = 0, a3 = 0;
#pragma unroll
    for (int r = 0; r < 32; r += 4) {
      u64 o0 = (u64)0 - (u64)((kb >> (r + 0)) & 1u);
      u64 o1 = (u64)0 - (u64)((kb >> (r + 1)) & 1u);
      u64 o2 = (u64)0 - (u64)((kb >> (r + 2)) & 1u);
      u64 o3 = (u64)0 - (u64)((kb >> (r + 3)) & 1u);
      a0 |= rb[(size_t)(r + 0) << 5] & o0;
      a1 |= rb[(size_t)(r + 1) << 5] & o1;
      a2 |= rb[(size_t)(r + 2) << 5] & o2;
      a3 |= rb[(size_t)(r + 3) << 5] & o3;
    }
    u64 supp = (a0 | a1) | (a2 | a3);
    supp |= __shfl_xor(supp, 32);
    kw &= ~supp;

    // early termination: kept rows in FINALIZED words 0..c
    int fin = (lane <= c) ? __popcll(kw) : 0;
    for (int o = 32; o; o >>= 1) fin += __shfl_xor(fin, o);
    if (fin >= MAXOUT) break;
  }

  int pc = (lane < 32) ? __popcll(kw) : 0;
  int pre = pc;
  for (int o = 1; o < 64; o <<= 1) {
    int v = __shfl_up(pre, o);
    if (lane >= o) pre += v;
  }
  int excl = pre - pc;
  int total = __shfl(pre, 63);

  float* ob = out;                              // [B,100,4]
  float* os = out + B_IMG * MAXOUT * 4;         // [B,100]
  float* ol = os + B_IMG * MAXOUT;              // [B,100]
  float* oi = ol + B_IMG * MAXOUT;              // [B,100]

  if (lane < 32) {
    u64 w = kw;
    int r = excl;
    while (w) {
      int bit = __ffsll((long long)w) - 1;
      w &= w - 1;
      if (r < MAXOUT) {
        int j = (lane << 6) + bit;
        size_t g = (size_t)b * K_NMS + j;
        float4 bx = raw4[g];
        int o = b * MAXOUT + r;
        ob[o * 4 + 0] = bx.x; ob[o * 4 + 1] = bx.y;
        ob[o * 4 + 2] = bx.z; ob[o * 4 + 3] = bx.w;
        os[o] = scoref[g];
        ol[o] = (float)labeli[g];
        oi[o] = (float)flati[g];
      }
      ++r;
    }
  }
  for (int r = total + lane; r < MAXOUT; r += 64) {
    int o = b * MAXOUT + r;
    ob[o * 4 + 0] = 0.f; ob[o * 4 + 1] = 0.f; ob[o * 4 + 2] = 0.f; ob[o * 4 + 3] = 0.f;
    os[o] = 0.f;
    ol[o] = -1.0f;
    oi[o] = -1.0f;
  }
}

// ---------------------------------------------------------------------------
extern "C" void kernel_launch(void* const* d_in, const int* in_sizes, int n_in,
                              void* d_out, int out_size, void* d_ws, size_t ws_size,
                              hipStream_t stream) {
  const float* cls = (const float*)d_in[0];
  const float* regs = (const float*)d_in[1];
  const float* props = (const float*)d_in[2];
  const int* pH = (const int*)d_in[3];
  const int* pW = (const int*)d_in[4];

  char* ws = (char*)d_ws;
  size_t o = 0;
  // --- zeroed region (contiguous) ---
  u32* hist = (u32*)(ws + o); o += (size_t)B_IMG * NBIN * sizeof(u32);      // 64 KB
  u32* gcnt = (u32*)(ws + o); o += (size_t)B_IMG * NSEG * sizeof(u32);      // 256 B
  u32* bincnt = (u32*)(ws + o); o += (size_t)B_IMG * NBIN * sizeof(u32);    // 64 KB
  u64* sorted = (u64*)(ws + o); o += (size_t)B_IMG * K_NMS * sizeof(u64);   // 64 KB
  int zero_words = (int)(o / sizeof(u32));
  // --- non-zeroed ---
  u32* cutg = (u32*)(ws + o); o += 256;
  u32* keptT = (u32*)(ws + o); o += 256;
  u32* binbase = (u32*)(ws + o); o += (size_t)B_IMG * NBIN * sizeof(u32);   // 64 KB
  u64* glist = (u64*)(ws + o); o += (size_t)B_IMG * NSEG * GSEGCAP * sizeof(u64);  // 2 MB
  u64* staging = (u64*)(ws + o); o += (size_t)B_IMG * STGN * sizeof(u64);   // 128 KB
  float4* raw4 = (float4*)(ws + o); o += (size_t)B_IMG * K_NMS * sizeof(float4);
  float4* off4 = (float4*)(ws + o); o += (size_t)B_IMG * K_NMS * sizeof(float4);
  float* area = (float*)(ws + o); o += (size_t)B_IMG * K_NMS * sizeof(float);
  float* scoref = (float*)(ws + o); o += (size_t)B_IMG * K_NMS * sizeof(float);
  int* labeli = (int*)(ws + o); o += (size_t)B_IMG * K_NMS * sizeof(int);
  int* flati = (int*)(ws + o); o += (size_t)B_IMG * K_NMS * sizeof(int);
  u64* masks = (u64*)(ws + o); o += (size_t)B_IMG * K_NMS * 32 * sizeof(u64);

  k_zero<<<(zero_words + 255) / 256, 256, 0, stream>>>(hist, zero_words);
  k_hist<<<B_IMG * N_ROI / 16, 1024, 0, stream>>>(cls, hist, gcnt, glist);
  k_cutbase<<<B_IMG, 1024, 0, stream>>>(hist, cutg, binbase, keptT);
  k_scatter<<<B_IMG * NSEG, 256, 0, stream>>>(gcnt, glist, cutg, binbase, bincnt, staging);
  k_rankwrite<<<B_IMG * STGN / 256, 256, 0, stream>>>(keptT, binbase, bincnt, staging, sorted);
  k_decode<<<B_IMG * K_NMS / 256, 256, 0, stream>>>(sorted, props, regs, pH, pW,
                                                    raw4, off4, area, scoref, labeli, flati);
  k_mask<<<B_IMG * K_NMS / 4, 256, 0, stream>>>(off4, area, masks);
  k_scanout<<<B_IMG, 64, 0, stream>>>(masks, scoref, raw4, labeli, flati, (float*)d_out);
}

// Round 9
// 84.010 us; speedup vs baseline: 13.3994x; 1.0307x over previous
//
#include <hip/hip_runtime.h>
#include <cstdint>
#include <cstddef>

#pragma clang fp contract(off)

typedef unsigned long long u64;
typedef unsigned int u32;

#define B_IMG 4
#define N_ROI 8192
#define NCLS 80
#define NCOL 81
#define K_NMS 2048
#define MAXOUT 100
#define THR_SCORE 0.05f
#define THR_IOU 0.5f

#define NBIN 4096
#define BIN_OFF 62771u  // (0x3D4CCCCD >> 14): bin of smallest float > 0.05f
#define NSEG 16
#define GSEGCAP 4096
#define STGN 4096  // staging capacity per image

// ---------------------------------------------------------------------------
// Kernel 0: zero hist + gcnt (16448 words).
// ---------------------------------------------------------------------------
__global__ __launch_bounds__(256) void k_zero(u32* __restrict__ p, int nwords) {
  int i = blockIdx.x * 256 + threadIdx.x;
  if (i < nwords) p[i] = 0;
}

// ---------------------------------------------------------------------------
// Softmax: bit-exact reference replication (IEEE, contract off, fixed order).
// ---------------------------------------------------------------------------
__device__ __forceinline__ void softmax_row(const float* __restrict__ row, int lane,
                                            float& s0, float& s1) {
  float v0 = row[lane];
  float v1 = (lane < NCOL - 64) ? row[64 + lane] : -1e38f;
  float m = fmaxf(v0, v1);
  for (int o = 32; o; o >>= 1) m = fmaxf(m, __shfl_xor(m, o));
  float e0 = expf(v0 - m);
  float e1 = (lane < NCOL - 64) ? expf(v1 - m) : 0.0f;
  float s = e0 + e1;
  for (int o = 32; o; o >>= 1) s += __shfl_xor(s, o);
  s0 = e0 / s;
  s1 = e1 / s;
}

// ---------------------------------------------------------------------------
// Kernel 1: softmax once per RoI; LDS-aggregated histogram AND key append.
// ---------------------------------------------------------------------------
__global__ __launch_bounds__(1024) void k_hist(const float* __restrict__ cls,
                                               u32* __restrict__ hist,
                                               u32* __restrict__ gcnt,
                                               u64* __restrict__ glist) {
#pragma clang fp contract(off)
  __shared__ u32 lh[NBIN];
  __shared__ u32 wbase[16];
  __shared__ u32 blkcnt;
  __shared__ u32 gbase;
  int t = threadIdx.x, wv = t >> 6, lane = t & 63;
  for (int i = t; i < NBIN; i += 1024) lh[i] = 0;
  if (t == 0) blkcnt = 0;
  __syncthreads();

  int wid = blockIdx.x * 16 + wv;  // 512 blocks per image
  int b = wid >> 13;
  int n = wid & (N_ROI - 1);

  float s0, s1;
  softmax_row(cls + (size_t)wid * NCOL, lane, s0, s1);
  bool c0 = s0 > THR_SCORE;
  bool c1 = (lane < 16) && (s1 > THR_SCORE);
  if (c0) atomicAdd(&lh[(__float_as_uint(s0) >> 14) - BIN_OFF], 1u);
  if (c1) atomicAdd(&lh[(__float_as_uint(s1) >> 14) - BIN_OFF], 1u);

  u64 b0 = __ballot(c0), b1 = __ballot(c1);
  int cnt = __popcll(b0) + __popcll(b1);
  if (lane == 0) wbase[wv] = atomicAdd(&blkcnt, (u32)cnt);
  __syncthreads();  // lh atomics + wbase complete

  int seg = blockIdx.x & (NSEG - 1);
  if (t == 0) gbase = atomicAdd(&gcnt[b * NSEG + seg], blkcnt);

  u32* gh = hist + (size_t)b * NBIN;
  for (int i = t; i < NBIN; i += 1024) {
    u32 c = lh[i];
    if (c) atomicAdd(&gh[i], c);
  }
  __syncthreads();  // gbase visible

  u32 base = gbase + wbase[wv];
  u64 lm = (1ull << lane) - 1ull;
  u64* seglist = glist + ((size_t)(b * NSEG + seg)) * GSEGCAP;
  if (c0) {
    u32 pos = base + (u32)__popcll(b0 & lm);
    if (pos < GSEGCAP) {
      u32 flat = (u32)(n * NCLS + lane);
      seglist[pos] = ((u64)__float_as_uint(s0) << 32) | (u32)(~flat);
    }
  }
  if (c1) {
    u32 pos = base + (u32)__popcll(b0) + (u32)__popcll(b1 & lm);
    if (pos < GSEGCAP) {
      u32 flat = (u32)(n * NCLS + 64 + lane);
      seglist[pos] = ((u64)__float_as_uint(s1) << 32) | (u32)(~flat);
    }
  }
}

// ---------------------------------------------------------------------------
// Kernel 2: per image -- cutoff bin, per-bin base offsets, kept count.
// Also zeroes bincnt (consumed by k_scatter, which runs after this).
// ---------------------------------------------------------------------------
__global__ __launch_bounds__(1024) void k_cutbase(const u32* __restrict__ hist,
                                                  u32* __restrict__ cutg,
                                                  u32* __restrict__ binbase,
                                                  u32* __restrict__ bincnt,
                                                  u32* __restrict__ keptT) {
  __shared__ u32 wsum[16];
  __shared__ int best;
  __shared__ u32 cutsh;
  int b = blockIdx.x, t = threadIdx.x;
  int lane = t & 63, wv = t >> 6;
  const u32* gh = hist + (size_t)b * NBIN;
  u32 v0 = gh[t * 4 + 0], v1 = gh[t * 4 + 1], v2 = gh[t * 4 + 2], v3 = gh[t * 4 + 3];
  u32 my = v0 + v1 + v2 + v3;
  u32 inc = my;
  for (int o = 1; o < 64; o <<= 1) {
    u32 x = __shfl_up(inc, o);
    if (lane >= o) inc += x;
  }
  if (lane == 63) wsum[wv] = inc;
  if (t == 0) best = 0;

  // zero bincnt for this image while the scan settles
  u32* bc = bincnt + (size_t)b * NBIN + t * 4;
  bc[0] = 0; bc[1] = 0; bc[2] = 0; bc[3] = 0;
  __syncthreads();

  u32 wpre = 0;
  for (int i = 0; i < wv; ++i) wpre += wsum[i];
  u32 total = 0;
  for (int i = 0; i < 16; ++i) total += wsum[i];
  u32 excl = wpre + (inc - my);  // prefix_excl(bin t*4)

  // base[bin] = count of keys in strictly higher bins
  u32* bb = binbase + (size_t)b * NBIN + t * 4;
  u32 pi = excl;
  pi += v0; bb[0] = total - pi;
  pi += v1; bb[1] = total - pi;
  pi += v2; bb[2] = total - pi;
  pi += v3; bb[3] = total - pi;

  if (total >= K_NMS) {
    u32 lim = total - K_NMS;
    u32 p = excl;
    int cand = -1;
    if (p <= lim) cand = t * 4 + 0; p += v0;
    if (p <= lim) cand = t * 4 + 1; p += v1;
    if (p <= lim) cand = t * 4 + 2; p += v2;
    if (p <= lim) cand = t * 4 + 3; p += v3;
    if (cand >= 0) atomicMax(&best, cand);
  }
  __syncthreads();
  if (t == 0) {
    u32 c = (total >= K_NMS) ? (u32)best : 0u;
    cutsh = c;
    cutg[b] = c;
  }
  __syncthreads();
  u32 c = cutsh;
  if (t == (int)(c >> 2)) {
    u32 pe = excl;
    int r = (int)(c & 3);
    if (r > 0) pe += v0;
    if (r > 1) pe += v1;
    if (r > 2) pe += v2;
    keptT[b] = total - pe;  // count of keys with bin >= cut
  }
}

// ---------------------------------------------------------------------------
// Kernel 3: scatter kept keys into their bin's slot range in staging.
// ---------------------------------------------------------------------------
__global__ __launch_bounds__(256) void k_scatter(const u32* __restrict__ gcnt,
                                                 const u64* __restrict__ glist,
                                                 const u32* __restrict__ cutg,
                                                 const u32* __restrict__ binbase,
                                                 u32* __restrict__ bincnt,
                                                 u64* __restrict__ staging) {
  int sid = blockIdx.x;  // 0 .. B*NSEG-1
  int b = sid >> 4;
  u32 c = cutg[b];
  u32 m = gcnt[sid];
  if (m > GSEGCAP) m = GSEGCAP;
  const u64* sl = glist + (size_t)sid * GSEGCAP;
  for (u32 i = threadIdx.x; i < m; i += 256) {
    u64 key = sl[i];
    u32 bin = (u32)(key >> 46) - BIN_OFF;
    if (bin >= c) {
      u32 slot = binbase[(size_t)b * NBIN + bin] +
                 atomicAdd(&bincnt[(size_t)b * NBIN + bin], 1u);
      if (slot < STGN) staging[(size_t)b * STGN + slot] = key;
    }
  }
}

// ---------------------------------------------------------------------------
// Kernel 4 (fused): exact in-bin rank -> global slot g; decode directly into
// the per-slot output arrays; slots [T, 2048) zero-filled. Replaces the old
// rankwrite + decode pair and the 'sorted' buffer.
// ---------------------------------------------------------------------------
__global__ __launch_bounds__(256) void k_rankdecode(const u32* __restrict__ keptT,
                                                    const u32* __restrict__ binbase,
                                                    const u32* __restrict__ bincnt,
                                                    const u64* __restrict__ staging,
                                                    const float* __restrict__ props,
                                                    const float* __restrict__ regs,
                                                    const int* __restrict__ pH,
                                                    const int* __restrict__ pW,
                                                    float4* __restrict__ raw4,
                                                    float4* __restrict__ off4,
                                                    float* __restrict__ area,
                                                    float* __restrict__ scoref,
                                                    int* __restrict__ labeli,
                                                    int* __restrict__ flati) {
#pragma clang fp contract(off)
  int p0 = blockIdx.x * 256 + threadIdx.x;  // 0 .. B*STGN-1
  int b = p0 >> 12;
  int i = p0 & (STGN - 1);
  u32 T = keptT[b];
  if (T > STGN) T = STGN;

  if ((u32)i >= T) {
    if ((u32)i < K_NMS) {  // zero-fill empty slot i
      size_t g = (size_t)b * K_NMS + i;
      raw4[g] = make_float4(0.f, 0.f, 0.f, 0.f);
      off4[g] = make_float4(0.f, 0.f, 0.f, 0.f);
      area[g] = 0.f; scoref[g] = -1.0f; labeli[g] = 0; flati[g] = 0;
    }
    return;
  }

  u64 key = staging[(size_t)b * STGN + i];
  u32 bin = (u32)(key >> 46) - BIN_OFF;
  u32 base = binbase[(size_t)b * NBIN + bin];
  u32 cnt = bincnt[(size_t)b * NBIN + bin];
  u32 end = base + cnt;
  if (end > STGN) end = STGN;
  u32 rank = 0;
  for (u32 j = base; j < end; ++j)
    rank += (staging[(size_t)b * STGN + j] > key) ? 1u : 0u;
  u32 gslot = base + rank;
  if (gslot >= K_NMS) return;
  size_t g = (size_t)b * K_NMS + gslot;

  float Hf = (float)pH[0];
  float Wf = (float)pW[0];
  float offc = fmaxf(Hf, Wf) + 1.0f;  // 1334

  u32 flat = ~(u32)(key & 0xFFFFFFFFull);
  float sc = __uint_as_float((u32)(key >> 32));
  int n = (int)(flat / NCLS);
  int c = (int)(flat - (u32)n * NCLS);

  float4 p = ((const float4*)props)[b * N_ROI + n];
  const float4 dl = *(const float4*)(regs + ((size_t)(b * N_ROI + n)) * (NCLS * 4) + c * 4);

  float mr = fabsf(logf(16.0f / 1000.0f));
  float dx = dl.x * 0.1f;
  float dy = dl.y * 0.1f;
  float dw = fminf(fmaxf(dl.z * 0.2f, -mr), mr);
  float dh = fminf(fmaxf(dl.w * 0.2f, -mr), mr);

  float px = (p.x + p.z) * 0.5f;
  float py = (p.y + p.w) * 0.5f;
  float pw = p.z - p.x;
  float ph = p.w - p.y;

  float tx = pw * dx; float gx = px + tx;
  float ty = ph * dy; float gy = py + ty;
  float gw = pw * expf(dw);
  float gh = ph * expf(dh);
  float hx = gw * 0.5f, hy = gh * 0.5f;

  float x1 = fminf(fmaxf(gx - hx, 0.0f), Wf);
  float y1 = fminf(fmaxf(gy - hy, 0.0f), Hf);
  float x2 = fminf(fmaxf(gx + hx, 0.0f), Wf);
  float y2 = fminf(fmaxf(gy + hy, 0.0f), Hf);

  raw4[g] = make_float4(x1, y1, x2, y2);

  float off = (float)c * offc;
  float ox1 = x1 + off, oy1 = y1 + off, ox2 = x2 + off, oy2 = y2 + off;
  off4[g] = make_float4(ox1, oy1, ox2, oy2);
  area[g] = fmaxf(ox2 - ox1, 0.0f) * fmaxf(oy2 - oy1, 0.0f);
  scoref[g] = sc;
  labeli[g] = c;
  flati[g] = (int)flat;
}

// ---------------------------------------------------------------------------
// Kernel 5: suppression bitmask, triangular (words below diagonal written 0).
// ---------------------------------------------------------------------------
__global__ __launch_bounds__(256) void k_mask(const float4* __restrict__ off4,
                                              const float* __restrict__ area,
                                              u64* __restrict__ masks) {
#pragma clang fp contract(off)
  int wave = threadIdx.x >> 6, lane = threadIdx.x & 63;
  int R = blockIdx.x * 4 + wave;  // 0 .. B*K-1
  int b = R >> 11, i = R & (K_NMS - 1);
  const float4* bb = off4 + (size_t)b * K_NMS;
  const float* aa = area + (size_t)b * K_NMS;
  float4 bi = bb[i];
  float ai = aa[i];
  u64 my = 0;
  for (int w = i >> 6; w < 32; ++w) {
    int j = (w << 6) + lane;
    float4 bj = bb[j];
    float lx = fmaxf(bi.x, bj.x);
    float ly = fmaxf(bi.y, bj.y);
    float rx = fminf(bi.z, bj.z);
    float ry = fminf(bi.w, bj.w);
    float ww = fmaxf(rx - lx, 0.0f);
    float hh = fmaxf(ry - ly, 0.0f);
    float inter = ww * hh;
    float uni = (ai + aa[j]) - inter;
    float iou = inter / fmaxf(uni, 1e-6f);
    bool sup = (j > i) && (iou > THR_IOU);
    u64 word = __ballot(sup);
    if (lane == w) my = word;
  }
  if (lane < 32) masks[((size_t)R << 5) + lane] = my;
}

// ---------------------------------------------------------------------------
// Kernel 6: greedy scan, chunked closure + early termination.
// keep-init computed from keptT (valid slots are exactly [0, min(T,2048))).
// Apply-loads issued into asm-pinned named registers BEFORE the closure so
// the compiler cannot sink them into the serial chain (R4 failure mode).
// ---------------------------------------------------------------------------
__global__ __launch_bounds__(64, 1) void k_scanout(const u64* __restrict__ masks,
                                                   const u32* __restrict__ keptT,
                                                   const float* __restrict__ scoref,
                                                   const float4* __restrict__ raw4,
                                                   const int* __restrict__ labeli,
                                                   const int* __restrict__ flati,
                                                   float* __restrict__ out) {
  int b = blockIdx.x;
  int lane = threadIdx.x;

  // keep init from keptT: slots [0, Tc) valid
  u32 Tc = keptT[b];
  if (Tc > K_NMS) Tc = K_NMS;
  u64 kw = 0;
  if (lane < 32) {
    int rem = (int)Tc - (lane << 6);
    kw = (rem >= 64) ? ~0ull : ((rem > 0) ? ((1ull << rem) - 1ull) : 0ull);
  }

  const u64* mrow = masks + ((size_t)b << 16);  // b * 2048 * 32
  int myw = lane & 31;
  int half = lane >> 5;

  u64 dnext = mrow[((size_t)lane << 5) + 0];

  for (int c = 0; c < 32; ++c) {
    u64 dcur = dnext;
    if (c < 31) dnext = mrow[((size_t)((c + 1) * 64 + lane) << 5) + (c + 1)];

    // ---- issue ALL apply-loads now; pin them so they can't be sunk ----
    const u64* rb = mrow + (((size_t)(c * 64 + half * 32)) << 5) + myw;
    u64 r0 = rb[0u << 5],  r1 = rb[1u << 5],  r2 = rb[2u << 5],  r3 = rb[3u << 5];
    u64 r4 = rb[4u << 5],  r5 = rb[5u << 5],  r6 = rb[6u << 5],  r7 = rb[7u << 5];
    u64 r8 = rb[8u << 5],  r9 = rb[9u << 5],  r10 = rb[10u << 5], r11 = rb[11u << 5];
    u64 r12 = rb[12u << 5], r13 = rb[13u << 5], r14 = rb[14u << 5], r15 = rb[15u << 5];
    u64 r16 = rb[16u << 5], r17 = rb[17u << 5], r18 = rb[18u << 5], r19 = rb[19u << 5];
    u64 r20 = rb[20u << 5], r21 = rb[21u << 5], r22 = rb[22u << 5], r23 = rb[23u << 5];
    u64 r24 = rb[24u << 5], r25 = rb[25u << 5], r26 = rb[26u << 5], r27 = rb[27u << 5];
    u64 r28 = rb[28u << 5], r29 = rb[29u << 5], r30 = rb[30u << 5], r31 = rb[31u << 5];
    asm volatile("" : "+v"(r0), "+v"(r1), "+v"(r2), "+v"(r3));
    asm volatile("" : "+v"(r4), "+v"(r5), "+v"(r6), "+v"(r7));
    asm volatile("" : "+v"(r8), "+v"(r9), "+v"(r10), "+v"(r11));
    asm volatile("" : "+v"(r12), "+v"(r13), "+v"(r14), "+v"(r15));
    asm volatile("" : "+v"(r16), "+v"(r17), "+v"(r18), "+v"(r19));
    asm volatile("" : "+v"(r20), "+v"(r21), "+v"(r22), "+v"(r23));
    asm volatile("" : "+v"(r24), "+v"(r25), "+v"(r26), "+v"(r27));
    asm volatile("" : "+v"(r28), "+v"(r29), "+v"(r30), "+v"(r31));

    // ---- (a) scalar closure of chunk c ----
    u32 dlo = (u32)dcur, dhi = (u32)(dcur >> 32);
    u64 kc = ((u64)(u32)__builtin_amdgcn_readlane((int)(u32)(kw >> 32), c) << 32) |
             (u32)__builtin_amdgcn_readlane((int)(u32)kw, c);
#pragma unroll
    for (int d = 0; d < 64; ++d) {
      u64 dg = ((u64)(u32)__builtin_amdgcn_readlane((int)dhi, d) << 32) |
               (u32)__builtin_amdgcn_readlane((int)dlo, d);
      u64 on = (u64)0 - ((kc >> d) & 1ull);
      kc &= ~(dg & on);
    }

    // ---- (b) apply suppression of kept rows ----
    u32 kb = half ? (u32)(kc >> 32) : (u32)kc;
#define ONB(r) ((u64)0 - (u64)((kb >> (r)) & 1u))
    u64 a0 = (r0 & ONB(0)) | (r1 & ONB(1)) | (r2 & ONB(2)) | (r3 & ONB(3)) |
             (r4 & ONB(4)) | (r5 & ONB(5)) | (r6 & ONB(6)) | (r7 & ONB(7));
    u64 a1 = (r8 & ONB(8)) | (r9 & ONB(9)) | (r10 & ONB(10)) | (r11 & ONB(11)) |
             (r12 & ONB(12)) | (r13 & ONB(13)) | (r14 & ONB(14)) | (r15 & ONB(15));
    u64 a2 = (r16 & ONB(16)) | (r17 & ONB(17)) | (r18 & ONB(18)) | (r19 & ONB(19)) |
             (r20 & ONB(20)) | (r21 & ONB(21)) | (r22 & ONB(22)) | (r23 & ONB(23));
    u64 a3 = (r24 & ONB(24)) | (r25 & ONB(25)) | (r26 & ONB(26)) | (r27 & ONB(27)) |
             (r28 & ONB(28)) | (r29 & ONB(29)) | (r30 & ONB(30)) | (r31 & ONB(31));
#undef ONB
    u64 supp = (a0 | a1) | (a2 | a3);
    supp |= __shfl_xor(supp, 32);
    kw &= ~supp;

    // early termination: kept rows in FINALIZED words 0..c
    int fin = (lane <= c) ? __popcll(kw) : 0;
    for (int o = 32; o; o >>= 1) fin += __shfl_xor(fin, o);
    if (fin >= MAXOUT) break;
  }

  int pc = (lane < 32) ? __popcll(kw) : 0;
  int pre = pc;
  for (int o = 1; o < 64; o <<= 1) {
    int v = __shfl_up(pre, o);
    if (lane >= o) pre += v;
  }
  int excl = pre - pc;
  int total = __shfl(pre, 63);

  float* ob = out;                              // [B,100,4]
  float* os = out + B_IMG * MAXOUT * 4;         // [B,100]
  float* ol = os + B_IMG * MAXOUT;              // [B,100]
  float* oi = ol + B_IMG * MAXOUT;              // [B,100]

  if (lane < 32) {
    u64 w = kw;
    int r = excl;
    while (w) {
      int bit = __ffsll((long long)w) - 1;
      w &= w - 1;
      if (r < MAXOUT) {
        int j = (lane << 6) + bit;
        size_t g = (size_t)b * K_NMS + j;
        float4 bx = raw4[g];
        int o = b * MAXOUT + r;
        ob[o * 4 + 0] = bx.x; ob[o * 4 + 1] = bx.y;
        ob[o * 4 + 2] = bx.z; ob[o * 4 + 3] = bx.w;
        os[o] = scoref[g];
        ol[o] = (float)labeli[g];
        oi[o] = (float)flati[g];
      }
      ++r;
    }
  }
  for (int r = total + lane; r < MAXOUT; r += 64) {
    int o = b * MAXOUT + r;
    ob[o * 4 + 0] = 0.f; ob[o * 4 + 1] = 0.f; ob[o * 4 + 2] = 0.f; ob[o * 4 + 3] = 0.f;
    os[o] = 0.f;
    ol[o] = -1.0f;
    oi[o] = -1.0f;
  }
}

// ---------------------------------------------------------------------------
extern "C" void kernel_launch(void* const* d_in, const int* in_sizes, int n_in,
                              void* d_out, int out_size, void* d_ws, size_t ws_size,
                              hipStream_t stream) {
  const float* cls = (const float*)d_in[0];
  const float* regs = (const float*)d_in[1];
  const float* props = (const float*)d_in[2];
  const int* pH = (const int*)d_in[3];
  const int* pW = (const int*)d_in[4];

  char* ws = (char*)d_ws;
  size_t o = 0;
  // --- zeroed region (contiguous): hist + gcnt ---
  u32* hist = (u32*)(ws + o); o += (size_t)B_IMG * NBIN * sizeof(u32);      // 64 KB
  u32* gcnt = (u32*)(ws + o); o += (size_t)B_IMG * NSEG * sizeof(u32);      // 256 B
  int zero_words = (int)(o / sizeof(u32));                                  // 16448
  // --- non-zeroed ---
  u32* bincnt = (u32*)(ws + o); o += (size_t)B_IMG * NBIN * sizeof(u32);    // zeroed in k_cutbase
  u32* cutg = (u32*)(ws + o); o += 256;
  u32* keptT = (u32*)(ws + o); o += 256;
  u32* binbase = (u32*)(ws + o); o += (size_t)B_IMG * NBIN * sizeof(u32);
  u64* glist = (u64*)(ws + o); o += (size_t)B_IMG * NSEG * GSEGCAP * sizeof(u64);  // 2 MB
  u64* staging = (u64*)(ws + o); o += (size_t)B_IMG * STGN * sizeof(u64);   // 128 KB
  float4* raw4 = (float4*)(ws + o); o += (size_t)B_IMG * K_NMS * sizeof(float4);
  float4* off4 = (float4*)(ws + o); o += (size_t)B_IMG * K_NMS * sizeof(float4);
  float* area = (float*)(ws + o); o += (size_t)B_IMG * K_NMS * sizeof(float);
  float* scoref = (float*)(ws + o); o += (size_t)B_IMG * K_NMS * sizeof(float);
  int* labeli = (int*)(ws + o); o += (size_t)B_IMG * K_NMS * sizeof(int);
  int* flati = (int*)(ws + o); o += (size_t)B_IMG * K_NMS * sizeof(int);
  u64* masks = (u64*)(ws + o); o += (size_t)B_IMG * K_NMS * 32 * sizeof(u64);

  k_zero<<<(zero_words + 255) / 256, 256, 0, stream>>>(hist, zero_words);
  k_hist<<<B_IMG * N_ROI / 16, 1024, 0, stream>>>(cls, hist, gcnt, glist);
  k_cutbase<<<B_IMG, 1024, 0, stream>>>(hist, cutg, binbase, bincnt, keptT);
  k_scatter<<<B_IMG * NSEG, 256, 0, stream>>>(gcnt, glist, cutg, binbase, bincnt, staging);
  k_rankdecode<<<B_IMG * STGN / 256, 256, 0, stream>>>(keptT, binbase, bincnt, staging,
                                                       props, regs, pH, pW,
                                                       raw4, off4, area, scoref, labeli, flati);
  k_mask<<<B_IMG * K_NMS / 4, 256, 0, stream>>>(off4, area, masks);
  k_scanout<<<B_IMG, 64, 0, stream>>>(masks, keptT, scoref, raw4, labeli, flati, (float*)d_out);
}